// Round 1
// baseline (2712.091 us; speedup 1.0000x reference)
//
#include <hip/hip_runtime.h>
#include <hip/hip_bf16.h>

#define TPB 256

// ---------------- graph preprocessing ----------------

__global__ void deg_kernel(const int* __restrict__ src, const int* __restrict__ dst,
                           float* __restrict__ deg_out, float* __restrict__ deg_in, int E) {
    int i = blockIdx.x * blockDim.x + threadIdx.x;
    if (i < E) {
        atomicAdd(&deg_out[src[i]], 1.0f);
        atomicAdd(&deg_in[dst[i]], 1.0f);
    }
}

// in-place: deg -> (deg>0 ? deg^-1/2 : 0) for both arrays
__global__ void norm_kernel(float* __restrict__ a, float* __restrict__ b, int n) {
    int i = blockIdx.x * blockDim.x + threadIdx.x;
    if (i < n) {
        float d = a[i]; a[i] = d > 0.f ? rsqrtf(d) : 0.f;
        float e = b[i]; b[i] = e > 0.f ? rsqrtf(e) : 0.f;
    }
}

// S[d] += norm_src[s] over edges
__global__ void s_kernel(const int* __restrict__ src, const int* __restrict__ dst,
                         const float* __restrict__ ns, float* __restrict__ S, int E) {
    int i = blockIdx.x * blockDim.x + threadIdx.x;
    if (i < E) atomicAdd(&S[dst[i]], ns[src[i]]);
}

// t = S * norm_dst (in place in S)
__global__ void t_kernel(float* __restrict__ S, const float* __restrict__ nd, int n) {
    int i = blockIdx.x * blockDim.x + threadIdx.x;
    if (i < n) S[i] *= nd[i];
}

// ---------------- small GEMV ----------------

// out[j] = dot(vec, Mat[j, :n]) + bias[j]; one block per row j
__global__ void gemv_rows(const float* __restrict__ vec, const float* __restrict__ Mat,
                          const float* __restrict__ bias, float* __restrict__ out, int n) {
    int j = blockIdx.x;
    const float* row = Mat + (size_t)j * n;
    float s = 0.f;
    for (int i = threadIdx.x; i < n; i += blockDim.x) s += vec[i] * row[i];
    __shared__ float red[TPB];
    red[threadIdx.x] = s;
    __syncthreads();
    for (int o = TPB / 2; o > 0; o >>= 1) {
        if (threadIdx.x < o) red[threadIdx.x] += red[threadIdx.x + o];
        __syncthreads();
    }
    if (threadIdx.x == 0) out[j] = red[0] + (bias ? bias[j] : 0.f);
}

// u[j] = sum_{i<FD} ce[i] * W1[i*IF + j]
__global__ void u_kernel(const float* __restrict__ ce, const float* __restrict__ W1,
                         float* __restrict__ u, int FD, int IF) {
    int j = blockIdx.x * blockDim.x + threadIdx.x;
    if (j >= IF) return;
    float s = 0.f;
    for (int i = 0; i < FD; i++) s += ce[i] * W1[(size_t)i * IF + j];
    u[j] = s;
}

// ---------------- tiled fp32 GEMM ----------------
// C[M,Nn] = rowscale[r] * (A[M,K] @ B) + (TU ? t[r]*u[c] : 0) + bias[c], opt relu
// BT=true: B stored [Nn,K] row-major (use B[j*K+k]); else [K,Nn].
template <bool BT, bool RELU, bool TU>
__global__ __launch_bounds__(256) void gemm_kernel(
    const float* __restrict__ A, const float* __restrict__ B,
    const float* __restrict__ bias, const float* __restrict__ rowscale,
    const float* __restrict__ tvec, const float* __restrict__ uvec,
    float* __restrict__ C, int M, int Nn, int K) {
    const int BM = 64, BN = 64, BK = 16;
    __shared__ float As[BK][BM + 1];
    __shared__ float Bs[BK][BN + 1];
    int tid = threadIdx.x;
    int tc = tid % 16, tr = tid / 16;  // 16x16 threads, each 4x4 outputs
    int row0 = blockIdx.y * BM, col0 = blockIdx.x * BN;
    float acc[4][4] = {};
    for (int k0 = 0; k0 < K; k0 += BK) {
        for (int i = 0; i < 4; i++) {
            int lin = tid + i * 256;
            int r = lin >> 4, c = lin & 15;
            int gr = row0 + r, gc = k0 + c;
            As[c][r] = (gr < M && gc < K) ? A[(size_t)gr * K + gc] : 0.f;
        }
        for (int i = 0; i < 4; i++) {
            int lin = tid + i * 256;
            int kk = lin >> 6, c = lin & 63;
            int gk = k0 + kk, gj = col0 + c;
            float bv = 0.f;
            if (gk < K && gj < Nn) bv = BT ? B[(size_t)gj * K + gk] : B[(size_t)gk * Nn + gj];
            Bs[kk][c] = bv;
        }
        __syncthreads();
#pragma unroll
        for (int kk = 0; kk < BK; kk++) {
            float a[4], b[4];
#pragma unroll
            for (int i = 0; i < 4; i++) a[i] = As[kk][tr * 4 + i];
#pragma unroll
            for (int j = 0; j < 4; j++) b[j] = Bs[kk][tc * 4 + j];
#pragma unroll
            for (int i = 0; i < 4; i++)
#pragma unroll
                for (int j = 0; j < 4; j++) acc[i][j] += a[i] * b[j];
        }
        __syncthreads();
    }
    for (int i = 0; i < 4; i++) {
        int r = row0 + tr * 4 + i;
        if (r >= M) continue;
        float rs = rowscale ? rowscale[r] : 1.f;
        float tv = TU ? tvec[r] : 0.f;
        for (int j = 0; j < 4; j++) {
            int c = col0 + tc * 4 + j;
            if (c >= Nn) continue;
            float v = acc[i][j] * rs + (bias ? bias[c] : 0.f);
            if (TU) v += tv * uvec[c];
            if (RELU) v = fmaxf(v, 0.f);
            C[(size_t)r * Nn + c] = v;
        }
    }
}

// ---------------- SpMM (edge-parallel, atomic) ----------------
// Y[dst] += norm_src[src] * X[src]  (F features); 4 edges/block, 64 lanes each
__global__ void spmm_kernel(const int* __restrict__ src, const int* __restrict__ dst,
                            const float* __restrict__ ns, const float* __restrict__ X,
                            float* __restrict__ Y, int E, int F) {
    int g = threadIdx.x >> 6;
    int lane = threadIdx.x & 63;
    int e = blockIdx.x * 4 + g;
    if (e >= E) return;
    int s = src[e], d = dst[e];
    float w = ns[s];
    const float* xr = X + (size_t)s * F;
    float* yr = Y + (size_t)d * F;
    for (int f = lane; f < F; f += 64) atomicAdd(&yr[f], w * xr[f]);
}

__global__ void spmm_scalar(const int* __restrict__ src, const int* __restrict__ dst,
                            const float* __restrict__ ns, const float* __restrict__ z,
                            float* __restrict__ oacc, int E) {
    int i = blockIdx.x * blockDim.x + threadIdx.x;
    if (i < E) {
        int s = src[i];
        atomicAdd(&oacc[dst[i]], ns[s] * z[s]);
    }
}

// z[n] = dot(X[n,:], w[:K]); one 64-lane group per node
__global__ void gemv_col(const float* __restrict__ X, const float* __restrict__ w,
                         float* __restrict__ z, int n, int K) {
    int g = threadIdx.x >> 6, lane = threadIdx.x & 63;
    int node = blockIdx.x * 4 + g;
    if (node >= n) return;
    const float* xr = X + (size_t)node * K;
    float s = 0.f;
    for (int k = lane; k < K; k += 64) s += xr[k] * w[k];
    for (int off = 32; off > 0; off >>= 1) s += __shfl_down(s, off);
    if (lane == 0) z[node] = s;
}

// o[n] = relu(nd[n]*oacc[n] + b3) in place
__global__ void o_kernel(float* __restrict__ oacc, const float* __restrict__ nd,
                         const float* __restrict__ b3, int n) {
    int i = blockIdx.x * blockDim.x + threadIdx.x;
    if (i < n) oacc[i] = fmaxf(nd[i] * oacc[i] + b3[0], 0.f);
}

// ---------------- launch ----------------

extern "C" void kernel_launch(void* const* d_in, const int* in_sizes, int n_in,
                              void* d_out, int out_size, void* d_ws, size_t ws_size,
                              hipStream_t stream) {
    const float* class_embed = (const float*)d_in[0];
    const float* all_glove   = (const float*)d_in[1];
    const float* W_word = (const float*)d_in[2];
    const float* b_word = (const float*)d_in[3];
    const float* W_img  = (const float*)d_in[4];
    const float* b_img  = (const float*)d_in[5];
    const float* W1 = (const float*)d_in[6];
    const float* b1 = (const float*)d_in[7];
    const float* W2 = (const float*)d_in[8];
    const float* b2 = (const float*)d_in[9];
    const float* W3 = (const float*)d_in[10];
    const float* b3 = (const float*)d_in[11];
    const float* W_fin = (const float*)d_in[12];
    const float* b_fin = (const float*)d_in[13];
    const int* src = (const int*)d_in[14];
    const int* dst = (const int*)d_in[15];

    const int N   = in_sizes[0];
    const int GLV = in_sizes[1] / N;
    const int FD  = in_sizes[5];   // 254
    const int IF  = in_sizes[7];   // 508
    const int E   = in_sizes[14];

    float* ws = (float*)d_ws;
    size_t p = 0;
    float* norm_src = ws + p; p += N;   // deg_out -> norm_src (in place)
    float* norm_dst = ws + p; p += N;   // deg_in  -> norm_dst
    float* Sv   = ws + p; p += N;       // S -> t (in place)
    float* ce   = ws + p; p += FD;
    float* u    = ws + p; p += IF;
    float* z    = ws + p; p += N;
    float* oacc = ws + p; p += N;
    p = (p + 3) & ~(size_t)3;
    float* r1 = ws + p; p += (size_t)N * IF;  // we | aggwe ; later agg2
    float* r2 = ws + p; p += (size_t)N * IF;  // h1 ; later h2
    float* we    = r1;
    float* aggwe = r1 + (size_t)N * FD;
    float* agg2  = r1;
    float* h1    = r2;
    float* h2    = r2;

    // zero degree/S/oacc small region
    hipMemsetAsync(ws, 0, (5 * (size_t)N + FD + IF) * sizeof(float), stream);

    int gE = (E + TPB - 1) / TPB;
    int gN = (N + TPB - 1) / TPB;
    deg_kernel<<<gE, TPB, 0, stream>>>(src, dst, norm_src, norm_dst, E);
    norm_kernel<<<gN, TPB, 0, stream>>>(norm_src, norm_dst, N);
    s_kernel<<<gE, TPB, 0, stream>>>(src, dst, norm_src, Sv, E);
    t_kernel<<<gN, TPB, 0, stream>>>(Sv, norm_dst, N);

    // ce = class_embed @ W_img.T + b_img   [FD]
    gemv_rows<<<FD, TPB, 0, stream>>>(class_embed, W_img, b_img, ce, N);
    // u = ce @ W1[:FD, :]                  [IF]
    u_kernel<<<(IF + TPB - 1) / TPB, TPB, 0, stream>>>(ce, W1, u, FD, IF);

    // we = all_glove @ W_word.T + b_word   [N, FD]
    {
        dim3 grid((FD + 63) / 64, (N + 63) / 64);
        gemm_kernel<true, false, false><<<grid, 256, 0, stream>>>(
            all_glove, W_word, b_word, nullptr, nullptr, nullptr, we, N, FD, GLV);
    }

    // SpMM1 (we half only): aggwe[d] += ns[s]*we[s]
    hipMemsetAsync(aggwe, 0, (size_t)N * FD * sizeof(float), stream);
    spmm_kernel<<<(E + 3) / 4, 256, 0, stream>>>(src, dst, norm_src, we, aggwe, E, FD);

    // h1 = relu(nd[r]*(aggwe @ W1[FD:,:]) + t[r]*u[c] + b1)   [N, IF]
    {
        dim3 grid((IF + 63) / 64, (N + 63) / 64);
        gemm_kernel<false, true, true><<<grid, 256, 0, stream>>>(
            aggwe, W1 + (size_t)FD * IF, b1, norm_dst, Sv, u, h1, N, IF, FD);
    }

    // SpMM2: agg2[d] += ns[s]*h1[s]   [N, IF]
    hipMemsetAsync(agg2, 0, (size_t)N * IF * sizeof(float), stream);
    spmm_kernel<<<(E + 3) / 4, 256, 0, stream>>>(src, dst, norm_src, h1, agg2, E, IF);

    // h2 = relu(nd[r]*(agg2 @ W2) + b2)   [N, IF]
    {
        dim3 grid((IF + 63) / 64, (N + 63) / 64);
        gemm_kernel<false, true, false><<<grid, 256, 0, stream>>>(
            agg2, W2, b2, norm_dst, nullptr, nullptr, h2, N, IF, IF);
    }

    // z = h2 @ W3   [N]
    gemv_col<<<(N + 3) / 4, 256, 0, stream>>>(h2, W3, z, N, IF);
    // oacc[d] += ns[s]*z[s] ; o = relu(nd*oacc + b3)
    spmm_scalar<<<gE, TPB, 0, stream>>>(src, dst, norm_src, z, oacc, E);
    o_kernel<<<gN, TPB, 0, stream>>>(oacc, norm_dst, b3, N);

    // out = o @ W_fin.T + b_fin   [FD]
    gemv_rows<<<FD, TPB, 0, stream>>>(oacc, W_fin, b_fin, (float*)d_out, N);
}

// Round 2
// 1126.857 us; speedup vs baseline: 2.4068x; 2.4068x over previous
//
#include <hip/hip_runtime.h>
#include <hip/hip_bf16.h>

#define TPB 256

// ---------------- graph preprocessing ----------------

// float degree accumulation (deg_out in ns[], deg_in in nd[])
__global__ void deg_kernel(const int* __restrict__ src, const int* __restrict__ dst,
                           float* __restrict__ deg_out, float* __restrict__ deg_in, int E) {
    int i = blockIdx.x * blockDim.x + threadIdx.x;
    if (i < E) {
        atomicAdd(&deg_out[src[i]], 1.0f);
        atomicAdd(&deg_in[dst[i]], 1.0f);
    }
}

// single-block exclusive scan over float degrees -> int row_ptr[0..n]
__global__ __launch_bounds__(1024) void scan_kernel(const float* __restrict__ deg,
                                                    int* __restrict__ rp, int n) {
    __shared__ int buf[1024];
    __shared__ int carry;
    if (threadIdx.x == 0) { carry = 0; rp[0] = 0; }
    __syncthreads();
    for (int base = 0; base < n; base += 1024) {
        int i = base + threadIdx.x;
        int v = (i < n) ? (int)deg[i] : 0;
        buf[threadIdx.x] = v;
        __syncthreads();
        for (int off = 1; off < 1024; off <<= 1) {
            int t = (threadIdx.x >= off) ? buf[threadIdx.x - off] : 0;
            __syncthreads();
            buf[threadIdx.x] += t;
            __syncthreads();
        }
        if (i < n) rp[i + 1] = carry + buf[threadIdx.x];
        __syncthreads();
        if (threadIdx.x == 0) carry += buf[1023];
        __syncthreads();
    }
}

// in-place: deg -> (deg>0 ? deg^-1/2 : 0) for both arrays
__global__ void norm_kernel(float* __restrict__ a, float* __restrict__ b, int n) {
    int i = blockIdx.x * blockDim.x + threadIdx.x;
    if (i < n) {
        float d = a[i]; a[i] = d > 0.f ? rsqrtf(d) : 0.f;
        float e = b[i]; b[i] = e > 0.f ? rsqrtf(e) : 0.f;
    }
}

// scatter edges into CSR buckets
__global__ void scatter_kernel(const int* __restrict__ src, const int* __restrict__ dst,
                               const int* __restrict__ rp, int* __restrict__ fill,
                               int* __restrict__ col, int E) {
    int i = blockIdx.x * blockDim.x + threadIdx.x;
    if (i < E) {
        int d = dst[i];
        int pos = rp[d] + atomicAdd(&fill[d], 1);
        col[pos] = src[i];
    }
}

// t[d] = nd[d] * sum_e ns[col[e]]   (CSR gather, one thread per node)
__global__ void st_kernel(const int* __restrict__ rp, const int* __restrict__ col,
                          const float* __restrict__ ns, const float* __restrict__ nd,
                          float* __restrict__ tv, int n) {
    int d = blockIdx.x * blockDim.x + threadIdx.x;
    if (d >= n) return;
    int beg = rp[d], end = rp[d + 1];
    float acc = 0.f;
    for (int e = beg; e < end; e++) acc += ns[col[e]];
    tv[d] = acc * nd[d];
}

// ---------------- small GEMV ----------------

// out[j] = dot(vec, Mat[j, :n]) + bias[j]; one block per row j
__global__ void gemv_rows(const float* __restrict__ vec, const float* __restrict__ Mat,
                          const float* __restrict__ bias, float* __restrict__ out, int n) {
    int j = blockIdx.x;
    const float* row = Mat + (size_t)j * n;
    float s = 0.f;
    for (int i = threadIdx.x; i < n; i += blockDim.x) s += vec[i] * row[i];
    __shared__ float red[TPB];
    red[threadIdx.x] = s;
    __syncthreads();
    for (int o = TPB / 2; o > 0; o >>= 1) {
        if (threadIdx.x < o) red[threadIdx.x] += red[threadIdx.x + o];
        __syncthreads();
    }
    if (threadIdx.x == 0) out[j] = red[0] + (bias ? bias[j] : 0.f);
}

// u[j] = sum_{i<FD} ce[i] * W1[i*IF + j]
__global__ void u_kernel(const float* __restrict__ ce, const float* __restrict__ W1,
                         float* __restrict__ u, int FD, int IF) {
    int j = blockIdx.x * blockDim.x + threadIdx.x;
    if (j >= IF) return;
    float s = 0.f;
    for (int i = 0; i < FD; i++) s += ce[i] * W1[(size_t)i * IF + j];
    u[j] = s;
}

// ---------------- tiled fp32 GEMM ----------------
// C[M,Nn] = rowscale[r] * (A[M,K] @ B) + (TU ? t[r]*u[c] : 0) + bias[c], opt relu
// BT=true: B stored [Nn,K] row-major (use B[j*K+k]); else [K,Nn].
template <bool BT, bool RELU, bool TU>
__global__ __launch_bounds__(256) void gemm_kernel(
    const float* __restrict__ A, const float* __restrict__ B,
    const float* __restrict__ bias, const float* __restrict__ rowscale,
    const float* __restrict__ tvec, const float* __restrict__ uvec,
    float* __restrict__ C, int M, int Nn, int K) {
    const int BM = 64, BN = 64, BK = 16;
    __shared__ float As[BK][BM + 1];
    __shared__ float Bs[BK][BN + 1];
    int tid = threadIdx.x;
    int tc = tid % 16, tr = tid / 16;  // 16x16 threads, each 4x4 outputs
    int row0 = blockIdx.y * BM, col0 = blockIdx.x * BN;
    float acc[4][4] = {};
    for (int k0 = 0; k0 < K; k0 += BK) {
        for (int i = 0; i < 4; i++) {
            int lin = tid + i * 256;
            int r = lin >> 4, c = lin & 15;
            int gr = row0 + r, gc = k0 + c;
            As[c][r] = (gr < M && gc < K) ? A[(size_t)gr * K + gc] : 0.f;
        }
        for (int i = 0; i < 4; i++) {
            int lin = tid + i * 256;
            int kk = lin >> 6, c = lin & 63;
            int gk = k0 + kk, gj = col0 + c;
            float bv = 0.f;
            if (gk < K && gj < Nn) bv = BT ? B[(size_t)gj * K + gk] : B[(size_t)gk * Nn + gj];
            Bs[kk][c] = bv;
        }
        __syncthreads();
#pragma unroll
        for (int kk = 0; kk < BK; kk++) {
            float a[4], b[4];
#pragma unroll
            for (int i = 0; i < 4; i++) a[i] = As[kk][tr * 4 + i];
#pragma unroll
            for (int j = 0; j < 4; j++) b[j] = Bs[kk][tc * 4 + j];
#pragma unroll
            for (int i = 0; i < 4; i++)
#pragma unroll
                for (int j = 0; j < 4; j++) acc[i][j] += a[i] * b[j];
        }
        __syncthreads();
    }
    for (int i = 0; i < 4; i++) {
        int r = row0 + tr * 4 + i;
        if (r >= M) continue;
        float rs = rowscale ? rowscale[r] : 1.f;
        float tv = TU ? tvec[r] : 0.f;
        for (int j = 0; j < 4; j++) {
            int c = col0 + tc * 4 + j;
            if (c >= Nn) continue;
            float v = acc[i][j] * rs + (bias ? bias[c] : 0.f);
            if (TU) v += tv * uvec[c];
            if (RELU) v = fmaxf(v, 0.f);
            C[(size_t)r * Nn + c] = v;
        }
    }
}

// ---------------- SpMM (CSR gather, no atomics) ----------------
// Y[d] = sum_{e in rp[d]..rp[d+1]} ns[col[e]] * X[col[e]]   float4 lanes (F = nu*4)
__global__ __launch_bounds__(128) void spmm_csr4(
    const int* __restrict__ rp, const int* __restrict__ col, const float* __restrict__ ns,
    const float* __restrict__ X, float* __restrict__ Y, int nu) {
    int d = blockIdx.x;
    int t = threadIdx.x;
    if (t >= nu) return;
    int beg = rp[d], end = rp[d + 1];
    float4 acc = make_float4(0.f, 0.f, 0.f, 0.f);
    for (int e = beg; e < end; e++) {
        int s = col[e];
        float w = ns[s];
        float4 x = ((const float4*)X)[(size_t)s * nu + t];
        acc.x += w * x.x; acc.y += w * x.y; acc.z += w * x.z; acc.w += w * x.w;
    }
    ((float4*)Y)[(size_t)d * nu + t] = acc;
}

// float2 variant (F = nu*2)
__global__ __launch_bounds__(128) void spmm_csr2(
    const int* __restrict__ rp, const int* __restrict__ col, const float* __restrict__ ns,
    const float* __restrict__ X, float* __restrict__ Y, int nu) {
    int d = blockIdx.x;
    int t = threadIdx.x;
    if (t >= nu) return;
    int beg = rp[d], end = rp[d + 1];
    float2 acc = make_float2(0.f, 0.f);
    for (int e = beg; e < end; e++) {
        int s = col[e];
        float w = ns[s];
        float2 x = ((const float2*)X)[(size_t)s * nu + t];
        acc.x += w * x.x; acc.y += w * x.y;
    }
    ((float2*)Y)[(size_t)d * nu + t] = acc;
}

// z[n] = dot(X[n,:], w[:K]); one 64-lane group per node
__global__ void gemv_col(const float* __restrict__ X, const float* __restrict__ w,
                         float* __restrict__ z, int n, int K) {
    int g = threadIdx.x >> 6, lane = threadIdx.x & 63;
    int node = blockIdx.x * 4 + g;
    if (node >= n) return;
    const float* xr = X + (size_t)node * K;
    float s = 0.f;
    for (int k = lane; k < K; k += 64) s += xr[k] * w[k];
    for (int off = 32; off > 0; off >>= 1) s += __shfl_down(s, off);
    if (lane == 0) z[node] = s;
}

// o[d] = relu(nd[d] * sum_e ns[col[e]]*z[col[e]] + b3)  (CSR gather)
__global__ void z_gather(const int* __restrict__ rp, const int* __restrict__ col,
                         const float* __restrict__ ns, const float* __restrict__ z,
                         const float* __restrict__ nd, const float* __restrict__ b3,
                         float* __restrict__ o, int n) {
    int d = blockIdx.x * blockDim.x + threadIdx.x;
    if (d >= n) return;
    int beg = rp[d], end = rp[d + 1];
    float acc = 0.f;
    for (int e = beg; e < end; e++) {
        int s = col[e];
        acc += ns[s] * z[s];
    }
    o[d] = fmaxf(nd[d] * acc + b3[0], 0.f);
}

// ---------------- launch ----------------

extern "C" void kernel_launch(void* const* d_in, const int* in_sizes, int n_in,
                              void* d_out, int out_size, void* d_ws, size_t ws_size,
                              hipStream_t stream) {
    const float* class_embed = (const float*)d_in[0];
    const float* all_glove   = (const float*)d_in[1];
    const float* W_word = (const float*)d_in[2];
    const float* b_word = (const float*)d_in[3];
    const float* W_img  = (const float*)d_in[4];
    const float* b_img  = (const float*)d_in[5];
    const float* W1 = (const float*)d_in[6];
    const float* b1 = (const float*)d_in[7];
    const float* W2 = (const float*)d_in[8];
    const float* b2 = (const float*)d_in[9];
    const float* W3 = (const float*)d_in[10];
    const float* b3 = (const float*)d_in[11];
    const float* W_fin = (const float*)d_in[12];
    const float* b_fin = (const float*)d_in[13];
    const int* src = (const int*)d_in[14];
    const int* dst = (const int*)d_in[15];

    const int N   = in_sizes[0];
    const int GLV = in_sizes[1] / N;
    const int FD  = in_sizes[5];   // 254
    const int IF  = in_sizes[7];   // 508
    const int E   = in_sizes[14];

    char* base = (char*)d_ws;
    size_t off = 0;
    auto alloc = [&](size_t bytes) -> void* {
        void* p = base + off;
        off = (off + bytes + 15) & ~(size_t)15;
        return p;
    };

    // zeroed region: ns, nd (degrees), fill
    float* ns  = (float*)alloc((size_t)N * 4);
    float* nd  = (float*)alloc((size_t)N * 4);
    int* fill  = (int*)alloc((size_t)N * 4);
    size_t zero_bytes = (size_t)((char*)(fill + N) - (char*)ns);
    // rest
    float* tv  = (float*)alloc((size_t)N * 4);
    float* ce  = (float*)alloc((size_t)FD * 4);
    float* u   = (float*)alloc((size_t)IF * 4);
    float* z   = (float*)alloc((size_t)N * 4);
    float* ov  = (float*)alloc((size_t)N * 4);
    int* rp    = (int*)alloc((size_t)(N + 1) * 4);
    int* col   = (int*)alloc((size_t)E * 4);
    float* r1  = (float*)alloc((size_t)N * IF * 4);
    float* r2  = (float*)alloc((size_t)N * IF * 4);

    float* we    = r1;
    float* aggwe = r1 + (size_t)N * FD;
    float* agg2  = r1;
    float* h1    = r2;
    float* h2    = r2;

    hipMemsetAsync(ns, 0, zero_bytes, stream);

    int gE = (E + TPB - 1) / TPB;
    int gN = (N + TPB - 1) / TPB;

    // CSR build + norms
    deg_kernel<<<gE, TPB, 0, stream>>>(src, dst, ns, nd, E);
    scan_kernel<<<1, 1024, 0, stream>>>(nd, rp, N);
    norm_kernel<<<gN, TPB, 0, stream>>>(ns, nd, N);
    scatter_kernel<<<gE, TPB, 0, stream>>>(src, dst, rp, fill, col, E);
    st_kernel<<<gN, TPB, 0, stream>>>(rp, col, ns, nd, tv, N);

    // ce = class_embed @ W_img.T + b_img   [FD]
    gemv_rows<<<FD, TPB, 0, stream>>>(class_embed, W_img, b_img, ce, N);
    // u = ce @ W1[:FD, :]                  [IF]
    u_kernel<<<(IF + TPB - 1) / TPB, TPB, 0, stream>>>(ce, W1, u, FD, IF);

    // we = all_glove @ W_word.T + b_word   [N, FD]
    {
        dim3 grid((FD + 63) / 64, (N + 63) / 64);
        gemm_kernel<true, false, false><<<grid, 256, 0, stream>>>(
            all_glove, W_word, b_word, nullptr, nullptr, nullptr, we, N, FD, GLV);
    }

    // SpMM1 (we half only): aggwe[d] = sum ns[s]*we[s]   [N, FD]
    spmm_csr2<<<N, 128, 0, stream>>>(rp, col, ns, we, aggwe, FD / 2);

    // h1 = relu(nd[r]*(aggwe @ W1[FD:,:]) + t[r]*u[c] + b1)   [N, IF]
    {
        dim3 grid((IF + 63) / 64, (N + 63) / 64);
        gemm_kernel<false, true, true><<<grid, 256, 0, stream>>>(
            aggwe, W1 + (size_t)FD * IF, b1, nd, tv, u, h1, N, IF, FD);
    }

    // SpMM2: agg2[d] = sum ns[s]*h1[s]   [N, IF]
    spmm_csr4<<<N, 128, 0, stream>>>(rp, col, ns, h1, agg2, IF / 4);

    // h2 = relu(nd[r]*(agg2 @ W2) + b2)   [N, IF]
    {
        dim3 grid((IF + 63) / 64, (N + 63) / 64);
        gemm_kernel<false, true, false><<<grid, 256, 0, stream>>>(
            agg2, W2, b2, nd, nullptr, nullptr, h2, N, IF, IF);
    }

    // z = h2 @ W3   [N]
    gemv_col<<<(N + 3) / 4, 256, 0, stream>>>(h2, W3, z, N, IF);
    // o = relu(nd * (CSR gather of ns*z) + b3)
    z_gather<<<gN, TPB, 0, stream>>>(rp, col, ns, z, nd, b3, ov, N);

    // out = o @ W_fin.T + b_fin   [FD]
    gemv_rows<<<FD, TPB, 0, stream>>>(ov, W_fin, b_fin, (float*)d_out, N);
}

// Round 3
// 596.982 us; speedup vs baseline: 4.5430x; 1.8876x over previous
//
#include <hip/hip_runtime.h>
#include <hip/hip_bf16.h>

#define TPB 256

typedef __attribute__((ext_vector_type(8))) short bf16x8_t;
typedef __attribute__((ext_vector_type(4))) float f32x4_t;
typedef __attribute__((ext_vector_type(8))) unsigned short u16x8_t;
typedef __attribute__((ext_vector_type(4))) unsigned short u16x4_t;

__device__ __forceinline__ float bf2f(unsigned short u) {
    return __uint_as_float(((unsigned)u) << 16);
}
__device__ __forceinline__ unsigned short f2bf(float f) {
    unsigned x = __float_as_uint(f);
    unsigned r = (x + 0x7fff + ((x >> 16) & 1)) >> 16;  // RNE
    return (unsigned short)r;
}

// ---------------- graph preprocessing ----------------

__global__ void deg_kernel(const int* __restrict__ src, const int* __restrict__ dst,
                           float* __restrict__ deg_out, float* __restrict__ deg_in, int E) {
    int i = blockIdx.x * blockDim.x + threadIdx.x;
    if (i < E) {
        atomicAdd(&deg_out[src[i]], 1.0f);
        atomicAdd(&deg_in[dst[i]], 1.0f);
    }
}

__global__ __launch_bounds__(1024) void scan_kernel(const float* __restrict__ deg,
                                                    int* __restrict__ rp, int n) {
    __shared__ int buf[1024];
    __shared__ int carry;
    if (threadIdx.x == 0) { carry = 0; rp[0] = 0; }
    __syncthreads();
    for (int base = 0; base < n; base += 1024) {
        int i = base + threadIdx.x;
        int v = (i < n) ? (int)deg[i] : 0;
        buf[threadIdx.x] = v;
        __syncthreads();
        for (int off = 1; off < 1024; off <<= 1) {
            int t = (threadIdx.x >= off) ? buf[threadIdx.x - off] : 0;
            __syncthreads();
            buf[threadIdx.x] += t;
            __syncthreads();
        }
        if (i < n) rp[i + 1] = carry + buf[threadIdx.x];
        __syncthreads();
        if (threadIdx.x == 0) carry += buf[1023];
        __syncthreads();
    }
}

__global__ void norm_kernel(float* __restrict__ a, float* __restrict__ b, int n) {
    int i = blockIdx.x * blockDim.x + threadIdx.x;
    if (i < n) {
        float d = a[i]; a[i] = d > 0.f ? rsqrtf(d) : 0.f;
        float e = b[i]; b[i] = e > 0.f ? rsqrtf(e) : 0.f;
    }
}

__global__ void scatter_kernel(const int* __restrict__ src, const int* __restrict__ dst,
                               const int* __restrict__ rp, int* __restrict__ fill,
                               int* __restrict__ col, int E) {
    int i = blockIdx.x * blockDim.x + threadIdx.x;
    if (i < E) {
        int d = dst[i];
        int pos = rp[d] + atomicAdd(&fill[d], 1);
        col[pos] = src[i];
    }
}

// t[d] = nd[d] * sum_e ns[col[e]]
__global__ void st_kernel(const int* __restrict__ rp, const int* __restrict__ col,
                          const float* __restrict__ ns, const float* __restrict__ nd,
                          float* __restrict__ tv, int n) {
    int d = blockIdx.x * blockDim.x + threadIdx.x;
    if (d >= n) return;
    int beg = rp[d], end = rp[d + 1];
    float acc = 0.f;
    for (int e = beg; e < end; e++) acc += ns[col[e]];
    tv[d] = acc * nd[d];
}

// ---------------- small GEMV (fp32) ----------------

__global__ void gemv_rows(const float* __restrict__ vec, const float* __restrict__ Mat,
                          const float* __restrict__ bias, float* __restrict__ out, int n) {
    int j = blockIdx.x;
    const float* row = Mat + (size_t)j * n;
    float s = 0.f;
    for (int i = threadIdx.x; i < n; i += blockDim.x) s += vec[i] * row[i];
    __shared__ float red[TPB];
    red[threadIdx.x] = s;
    __syncthreads();
    for (int o = TPB / 2; o > 0; o >>= 1) {
        if (threadIdx.x < o) red[threadIdx.x] += red[threadIdx.x + o];
        __syncthreads();
    }
    if (threadIdx.x == 0) out[j] = red[0] + (bias ? bias[j] : 0.f);
}

__global__ void u_kernel(const float* __restrict__ ce, const float* __restrict__ W1,
                         float* __restrict__ u, int FD, int IF) {
    int j = blockIdx.x * blockDim.x + threadIdx.x;
    if (j >= IF) return;
    float s = 0.f;
    for (int i = 0; i < FD; i++) s += ce[i] * W1[(size_t)i * IF + j];
    u[j] = s;
}

// ---------------- conversion kernels ----------------

// out[row][c] = (row<irows && c<icols) ? in[row*icols+c] : 0, bf16; grid.y = orows
__global__ void pad_convert(const float* __restrict__ in, int icols, int irows,
                            unsigned short* __restrict__ out, int ocols) {
    int row = blockIdx.y;
    int c = blockIdx.x * 64 + threadIdx.x;
    if (c >= ocols) return;
    float v = (row < irows && c < icols) ? in[(size_t)row * icols + c] : 0.f;
    out[(size_t)row * ocols + c] = f2bf(v);
}

// out[n][k] = W[k][n] (bf16), zero-padded to [orows][ocols]
__global__ void transpose_pad(const float* __restrict__ W, int rows, int cols, int ldw,
                              unsigned short* __restrict__ out, int orows, int ocols) {
    __shared__ float tile[32][33];
    int k0 = blockIdx.x * 32, n0 = blockIdx.y * 32;
    int tx = threadIdx.x, ty = threadIdx.y;  // 32 x 8
    for (int i = 0; i < 32; i += 8) {
        int k = k0 + ty + i, n = n0 + tx;
        tile[ty + i][tx] = (k < rows && n < cols) ? W[(size_t)k * ldw + n] : 0.f;
    }
    __syncthreads();
    for (int i = 0; i < 32; i += 8) {
        int n = n0 + ty + i, k = k0 + tx;
        if (n < orows && k < ocols) out[(size_t)n * ocols + k] = f2bf(tile[tx][ty + i]);
    }
}

// ---------------- bf16 MFMA GEMM ----------------
// C[M][Cld] (bf16) = relu?( rowscale[r]*(A@B) + t[r]*u[c] + bias[c] )
// A: [M][Kp] bf16. Bt: [Np][Kp] bf16 (B column-major), Np = gridX*128. Kp % 32 == 0.
__global__ __launch_bounds__(256) void mfma_gemm(
    const unsigned short* __restrict__ A, const unsigned short* __restrict__ Bt,
    const float* __restrict__ bias, const float* __restrict__ rowscale,
    const float* __restrict__ tvec, const float* __restrict__ uvec,
    unsigned short* __restrict__ C, int M, int Nn, int Kp, int Cld, int relu) {
    __shared__ unsigned short As[128 * 32];
    __shared__ unsigned short Bs[128 * 32];
    int tid = threadIdx.x;
    int lane = tid & 63;
    int wave = tid >> 6;
    int wm = wave >> 1, wn = wave & 1;  // 2x2 waves, each 64x64
    int lg = lane >> 4, lt = lane & 15;
    int row0 = blockIdx.y * 128, col0 = blockIdx.x * 128;

    f32x4_t acc[4][4] = {};

    int nk = Kp >> 5;
    for (int kp = 0; kp < nk; kp++) {
        int k0 = kp << 5;
        // stage 128x32 bf16 tiles; 512 chunks of 16B each, 2 per thread
#pragma unroll
        for (int i = 0; i < 2; i++) {
            int cid = tid + i * 256;
            int r = cid >> 2, c = cid & 3;
            int sw = c ^ ((r >> 1) & 3);
            int4 av = make_int4(0, 0, 0, 0);
            int grA = row0 + r;
            if (grA < M) av = *(const int4*)(A + (size_t)grA * Kp + k0 + (c << 3));
            *(int4*)(As + r * 32 + sw * 8) = av;
            int4 bv = *(const int4*)(Bt + (size_t)(col0 + r) * Kp + k0 + (c << 3));
            *(int4*)(Bs + r * 32 + sw * 8) = bv;
        }
        __syncthreads();
        bf16x8_t af[4], bfr[4];
#pragma unroll
        for (int mi = 0; mi < 4; mi++) {
            int r = wm * 64 + mi * 16 + lt;
            int sw = lg ^ ((r >> 1) & 3);
            af[mi] = *(const bf16x8_t*)(As + r * 32 + sw * 8);
        }
#pragma unroll
        for (int ni = 0; ni < 4; ni++) {
            int r = wn * 64 + ni * 16 + lt;
            int sw = lg ^ ((r >> 1) & 3);
            bfr[ni] = *(const bf16x8_t*)(Bs + r * 32 + sw * 8);
        }
#pragma unroll
        for (int mi = 0; mi < 4; mi++)
#pragma unroll
            for (int ni = 0; ni < 4; ni++)
                acc[mi][ni] = __builtin_amdgcn_mfma_f32_16x16x32_bf16(af[mi], bfr[ni], acc[mi][ni], 0, 0, 0);
        __syncthreads();
    }

    // epilogue: D row = lg*4+reg, col = lt  (within each 16x16 frag)
#pragma unroll
    for (int mi = 0; mi < 4; mi++) {
#pragma unroll
        for (int r = 0; r < 4; r++) {
            int row = row0 + wm * 64 + mi * 16 + lg * 4 + r;
            if (row >= M) continue;
            float rs = rowscale ? rowscale[row] : 1.f;
            float tvr = tvec ? tvec[row] : 0.f;
#pragma unroll
            for (int ni = 0; ni < 4; ni++) {
                int colb = col0 + wn * 64 + ni * 16 + lt;
                float v = 0.f;
                if (colb < Nn) {
                    v = acc[mi][ni][r] * rs;
                    if (bias) v += bias[colb];
                    if (tvec) v += tvr * uvec[colb];
                    if (relu) v = fmaxf(v, 0.f);
                }
                C[(size_t)row * Cld + colb] = f2bf(v);
            }
        }
    }
}

// ---------------- SpMM (CSR gather, bf16) ----------------
// one 64-lane wave per node; Fp = 512 (8/lane) or 256 (4/lane)
__global__ __launch_bounds__(256) void spmm_bf16_512(
    const int* __restrict__ rp, const int* __restrict__ col, const float* __restrict__ ns,
    const unsigned short* __restrict__ X, unsigned short* __restrict__ Y, int n) {
    int node = blockIdx.x * 4 + (threadIdx.x >> 6);
    if (node >= n) return;
    int lane = threadIdx.x & 63;
    const int Fp = 512;
    int beg = rp[node], end = rp[node + 1];
    float acc[8] = {};
    int e = beg;
    for (; e + 1 < end; e += 2) {
        int s0 = col[e], s1 = col[e + 1];
        float w0 = ns[s0], w1 = ns[s1];
        u16x8_t v0 = *(const u16x8_t*)(X + (size_t)s0 * Fp + lane * 8);
        u16x8_t v1 = *(const u16x8_t*)(X + (size_t)s1 * Fp + lane * 8);
#pragma unroll
        for (int c = 0; c < 8; c++) acc[c] += w0 * bf2f(v0[c]);
#pragma unroll
        for (int c = 0; c < 8; c++) acc[c] += w1 * bf2f(v1[c]);
    }
    if (e < end) {
        int s0 = col[e];
        float w0 = ns[s0];
        u16x8_t v0 = *(const u16x8_t*)(X + (size_t)s0 * Fp + lane * 8);
#pragma unroll
        for (int c = 0; c < 8; c++) acc[c] += w0 * bf2f(v0[c]);
    }
    u16x8_t o;
#pragma unroll
    for (int c = 0; c < 8; c++) o[c] = f2bf(acc[c]);
    *(u16x8_t*)(Y + (size_t)node * Fp + lane * 8) = o;
}

__global__ __launch_bounds__(256) void spmm_bf16_256(
    const int* __restrict__ rp, const int* __restrict__ col, const float* __restrict__ ns,
    const unsigned short* __restrict__ X, unsigned short* __restrict__ Y, int n) {
    int node = blockIdx.x * 4 + (threadIdx.x >> 6);
    if (node >= n) return;
    int lane = threadIdx.x & 63;
    const int Fp = 256;
    int beg = rp[node], end = rp[node + 1];
    float acc[4] = {};
    int e = beg;
    for (; e + 1 < end; e += 2) {
        int s0 = col[e], s1 = col[e + 1];
        float w0 = ns[s0], w1 = ns[s1];
        u16x4_t v0 = *(const u16x4_t*)(X + (size_t)s0 * Fp + lane * 4);
        u16x4_t v1 = *(const u16x4_t*)(X + (size_t)s1 * Fp + lane * 4);
#pragma unroll
        for (int c = 0; c < 4; c++) acc[c] += w0 * bf2f(v0[c]);
#pragma unroll
        for (int c = 0; c < 4; c++) acc[c] += w1 * bf2f(v1[c]);
    }
    if (e < end) {
        int s0 = col[e];
        float w0 = ns[s0];
        u16x4_t v0 = *(const u16x4_t*)(X + (size_t)s0 * Fp + lane * 4);
#pragma unroll
        for (int c = 0; c < 4; c++) acc[c] += w0 * bf2f(v0[c]);
    }
    u16x4_t o;
#pragma unroll
    for (int c = 0; c < 4; c++) o[c] = f2bf(acc[c]);
    *(u16x4_t*)(Y + (size_t)node * Fp + lane * 4) = o;
}

// ---------------- z path ----------------

// z[node] = dot(h2[node, :K], w3); h2 bf16 with row stride ld
__global__ void gemv_col_bf(const unsigned short* __restrict__ X, const float* __restrict__ w,
                            float* __restrict__ z, int n, int K, int ld) {
    int g = threadIdx.x >> 6, lane = threadIdx.x & 63;
    int node = blockIdx.x * 4 + g;
    if (node >= n) return;
    const unsigned short* xr = X + (size_t)node * ld;
    float s = 0.f;
    for (int k = lane; k < K; k += 64) s += bf2f(xr[k]) * w[k];
    for (int off = 32; off > 0; off >>= 1) s += __shfl_down(s, off);
    if (lane == 0) z[node] = s;
}

__global__ void z_gather(const int* __restrict__ rp, const int* __restrict__ col,
                         const float* __restrict__ ns, const float* __restrict__ z,
                         const float* __restrict__ nd, const float* __restrict__ b3,
                         float* __restrict__ o, int n) {
    int d = blockIdx.x * blockDim.x + threadIdx.x;
    if (d >= n) return;
    int beg = rp[d], end = rp[d + 1];
    float acc = 0.f;
    for (int e = beg; e < end; e++) {
        int s = col[e];
        acc += ns[s] * z[s];
    }
    o[d] = fmaxf(nd[d] * acc + b3[0], 0.f);
}

// ---------------- launch ----------------

extern "C" void kernel_launch(void* const* d_in, const int* in_sizes, int n_in,
                              void* d_out, int out_size, void* d_ws, size_t ws_size,
                              hipStream_t stream) {
    const float* class_embed = (const float*)d_in[0];
    const float* all_glove   = (const float*)d_in[1];
    const float* W_word = (const float*)d_in[2];
    const float* b_word = (const float*)d_in[3];
    const float* W_img  = (const float*)d_in[4];
    const float* b_img  = (const float*)d_in[5];
    const float* W1 = (const float*)d_in[6];
    const float* b1 = (const float*)d_in[7];
    const float* W2 = (const float*)d_in[8];
    const float* b2 = (const float*)d_in[9];
    const float* W3 = (const float*)d_in[10];
    const float* b3 = (const float*)d_in[11];
    const float* W_fin = (const float*)d_in[12];
    const float* b_fin = (const float*)d_in[13];
    const int* src = (const int*)d_in[14];
    const int* dst = (const int*)d_in[15];

    const int N   = in_sizes[0];
    const int GLV = in_sizes[1] / N;   // 300
    const int FD  = in_sizes[5];       // 254
    const int IF  = in_sizes[7];       // 508
    const int E   = in_sizes[14];

    const int GLVp = 320;   // pad to mult of 32
    const int FDp  = 256;
    const int IFp  = 512;

    char* base = (char*)d_ws;
    size_t off = 0;
    auto alloc = [&](size_t bytes) -> void* {
        void* p = base + off;
        off = (off + bytes + 255) & ~(size_t)255;
        return p;
    };

    // zero region: ns, nd, fill (contiguous)
    float* ns  = (float*)alloc((size_t)N * 4);
    float* nd  = (float*)alloc((size_t)N * 4);
    int* fill  = (int*)alloc((size_t)N * 4);
    size_t zero_bytes = (size_t)((char*)(fill + N) - (char*)ns);
    float* tv  = (float*)alloc((size_t)N * 4);
    float* ce  = (float*)alloc((size_t)FD * 4);
    float* u   = (float*)alloc((size_t)IF * 4);
    float* z   = (float*)alloc((size_t)N * 4);
    float* ov  = (float*)alloc((size_t)N * 4);
    int* rp    = (int*)alloc((size_t)(N + 1) * 4);
    int* col   = (int*)alloc((size_t)E * 4);
    unsigned short* WwP  = (unsigned short*)alloc((size_t)FDp * GLVp * 2);  // [256][320]
    unsigned short* W1hT = (unsigned short*)alloc((size_t)IFp * FDp * 2);   // [512][256]
    unsigned short* W2T  = (unsigned short*)alloc((size_t)IFp * IFp * 2);   // [512][512]
    // big regions: A=glove_bf, B=we (adjacent), D=h1/h2
    unsigned short* glove_bf = (unsigned short*)alloc((size_t)N * GLVp * 2);  // 12.8 MB
    unsigned short* we       = (unsigned short*)alloc((size_t)N * FDp * 2);   // 10.24 MB
    unsigned short* h12      = (unsigned short*)alloc((size_t)N * IFp * 2);   // 20.48 MB
    unsigned short* aggwe = glove_bf;             // [N][256], after glove dead
    unsigned short* agg2  = glove_bf;             // [N][512], spans glove+we (both dead)
    unsigned short* h1 = h12;
    unsigned short* h2 = h12;

    hipMemsetAsync(ns, 0, zero_bytes, stream);

    int gE = (E + TPB - 1) / TPB;
    int gN = (N + TPB - 1) / TPB;

    // CSR build + norms
    deg_kernel<<<gE, TPB, 0, stream>>>(src, dst, ns, nd, E);
    scan_kernel<<<1, 1024, 0, stream>>>(nd, rp, N);
    norm_kernel<<<gN, TPB, 0, stream>>>(ns, nd, N);
    scatter_kernel<<<gE, TPB, 0, stream>>>(src, dst, rp, fill, col, E);
    st_kernel<<<gN, TPB, 0, stream>>>(rp, col, ns, nd, tv, N);

    // ce = class_embed @ W_img.T + b_img ; u = ce @ W1[:FD, :]
    gemv_rows<<<FD, TPB, 0, stream>>>(class_embed, W_img, b_img, ce, N);
    u_kernel<<<(IF + TPB - 1) / TPB, TPB, 0, stream>>>(ce, W1, u, FD, IF);

    // weight conversions
    {
        dim3 g((GLVp + 63) / 64, N);
        pad_convert<<<g, 64, 0, stream>>>(all_glove, GLV, N, glove_bf, GLVp);
    }
    {
        dim3 g((GLVp + 63) / 64, FDp);
        pad_convert<<<g, 64, 0, stream>>>(W_word, GLV, FD, WwP, GLVp);
    }
    {
        dim3 g(FDp / 32, IFp / 32);  // (k-tiles, n-tiles)
        transpose_pad<<<g, dim3(32, 8), 0, stream>>>(W1 + (size_t)FD * IF, FD, IF, IF, W1hT, IFp, FDp);
    }
    {
        dim3 g(IFp / 32, IFp / 32);
        transpose_pad<<<g, dim3(32, 8), 0, stream>>>(W2, IF, IF, IF, W2T, IFp, IFp);
    }

    int mtiles = (N + 127) / 128;

    // we = all_glove @ W_word.T + b_word   [N][256] bf16
    {
        dim3 g(FDp / 128, mtiles);
        mfma_gemm<<<g, 256, 0, stream>>>(glove_bf, WwP, b_word, nullptr, nullptr, nullptr,
                                         we, N, FD, GLVp, FDp, 0);
    }
    // SpMM1: aggwe = sum ns[s]*we[s]   [N][256]
    spmm_bf16_256<<<(N + 3) / 4, 256, 0, stream>>>(rp, col, ns, we, aggwe, N);
    // h1 = relu(nd[r]*(aggwe @ W1[FD:,:]) + tv[r]*u[c] + b1)   [N][512]
    {
        dim3 g(IFp / 128, mtiles);
        mfma_gemm<<<g, 256, 0, stream>>>(aggwe, W1hT, b1, nd, tv, u, h1, N, IF, FDp, IFp, 1);
    }
    // SpMM2: agg2 = sum ns[s]*h1[s]   [N][512]
    spmm_bf16_512<<<(N + 3) / 4, 256, 0, stream>>>(rp, col, ns, h1, agg2, N);
    // h2 = relu(nd[r]*(agg2 @ W2) + b2)   [N][512]
    {
        dim3 g(IFp / 128, mtiles);
        mfma_gemm<<<g, 256, 0, stream>>>(agg2, W2T, b2, nd, nullptr, nullptr, h2, N, IF, IFp, IFp, 1);
    }
    // z = h2 @ W3
    gemv_col_bf<<<(N + 3) / 4, 256, 0, stream>>>(h2, W3, z, N, IF, IFp);
    // o = relu(nd * gather(ns*z) + b3)
    z_gather<<<gN, TPB, 0, stream>>>(rp, col, ns, z, nd, b3, ov, N);
    // out = o @ W_fin.T + b_fin
    gemv_rows<<<FD, TPB, 0, stream>>>(ov, W_fin, b_fin, (float*)d_out, N);
}

// Round 4
// 429.743 us; speedup vs baseline: 6.3110x; 1.3892x over previous
//
#include <hip/hip_runtime.h>
#include <hip/hip_bf16.h>

#define TPB 256

typedef __attribute__((ext_vector_type(8))) short bf16x8_t;
typedef __attribute__((ext_vector_type(4))) float f32x4_t;
typedef __attribute__((ext_vector_type(8))) unsigned short u16x8_t;
typedef __attribute__((ext_vector_type(4))) unsigned short u16x4_t;

__device__ __forceinline__ float bf2f(unsigned short u) {
    return __uint_as_float(((unsigned)u) << 16);
}
__device__ __forceinline__ unsigned short f2bf(float f) {
    unsigned x = __float_as_uint(f);
    unsigned r = (x + 0x7fff + ((x >> 16) & 1)) >> 16;  // RNE
    return (unsigned short)r;
}

// ---------------- graph preprocessing ----------------

__global__ void deg_kernel(const int* __restrict__ src, const int* __restrict__ dst,
                           float* __restrict__ deg_out, float* __restrict__ deg_in, int E) {
    int i = blockIdx.x * blockDim.x + threadIdx.x;
    if (i < E) {
        atomicAdd(&deg_out[src[i]], 1.0f);
        atomicAdd(&deg_in[dst[i]], 1.0f);
    }
}

// multi-block scan, phase 1: block-local inclusive scan -> rp[i+1]; block sum -> bsum[b]
__global__ __launch_bounds__(1024) void scan1(const float* __restrict__ deg,
                                              int* __restrict__ rp, int* __restrict__ bsum, int n) {
    __shared__ int buf[1024];
    int b = blockIdx.x;
    int i = b * 1024 + threadIdx.x;
    int v = (i < n) ? (int)deg[i] : 0;
    buf[threadIdx.x] = v;
    __syncthreads();
    for (int off = 1; off < 1024; off <<= 1) {
        int t = (threadIdx.x >= off) ? buf[threadIdx.x - off] : 0;
        __syncthreads();
        buf[threadIdx.x] += t;
        __syncthreads();
    }
    if (i < n) rp[i + 1] = buf[threadIdx.x];
    if (threadIdx.x == 1023) bsum[b] = buf[1023];
    if (b == 0 && threadIdx.x == 0) rp[0] = 0;
}

// phase 2: single-wave inclusive scan of block sums (nb <= 64)
__global__ void scan2(int* __restrict__ bsum, int nb) {
    int lane = threadIdx.x;
    int v = (lane < nb) ? bsum[lane] : 0;
    for (int off = 1; off < 64; off <<= 1) {
        int t = __shfl_up(v, off);
        if (lane >= off) v += t;
    }
    if (lane < nb) bsum[lane] = v;
}

// phase 3: add previous-block inclusive sums
__global__ __launch_bounds__(1024) void scan3(int* __restrict__ rp, const int* __restrict__ bsum, int n) {
    int b = blockIdx.x;
    if (b == 0) return;
    int i = b * 1024 + threadIdx.x;
    if (i < n) rp[i + 1] += bsum[b - 1];
}

__global__ void norm_kernel(float* __restrict__ a, float* __restrict__ b, int n) {
    int i = blockIdx.x * blockDim.x + threadIdx.x;
    if (i < n) {
        float d = a[i]; a[i] = d > 0.f ? rsqrtf(d) : 0.f;
        float e = b[i]; b[i] = e > 0.f ? rsqrtf(e) : 0.f;
    }
}

__global__ void scatter_kernel(const int* __restrict__ src, const int* __restrict__ dst,
                               const int* __restrict__ rp, int* __restrict__ fill,
                               int* __restrict__ col, int E) {
    int i = blockIdx.x * blockDim.x + threadIdx.x;
    if (i < E) {
        int d = dst[i];
        int pos = rp[d] + atomicAdd(&fill[d], 1);
        col[pos] = src[i];
    }
}

// t[d] = nd[d] * sum_e ns[col[e]]   (wave per node, shfl reduce)
__global__ __launch_bounds__(256) void st_kernel(const int* __restrict__ rp, const int* __restrict__ col,
                                                 const float* __restrict__ ns, const float* __restrict__ nd,
                                                 float* __restrict__ tv, int n) {
    int d = blockIdx.x * 4 + (threadIdx.x >> 6);
    if (d >= n) return;
    int lane = threadIdx.x & 63;
    int beg = rp[d], end = rp[d + 1];
    float acc = 0.f;
    for (int e = beg + lane; e < end; e += 64) acc += ns[col[e]];
    for (int off = 32; off > 0; off >>= 1) acc += __shfl_down(acc, off);
    if (lane == 0) tv[d] = acc * nd[d];
}

// ---------------- small GEMV (fp32) ----------------

__global__ void gemv_rows(const float* __restrict__ vec, const float* __restrict__ Mat,
                          const float* __restrict__ bias, float* __restrict__ out, int n) {
    int j = blockIdx.x;
    const float* row = Mat + (size_t)j * n;
    float s = 0.f;
    for (int i = threadIdx.x; i < n; i += blockDim.x) s += vec[i] * row[i];
    __shared__ float red[TPB];
    red[threadIdx.x] = s;
    __syncthreads();
    for (int o = TPB / 2; o > 0; o >>= 1) {
        if (threadIdx.x < o) red[threadIdx.x] += red[threadIdx.x + o];
        __syncthreads();
    }
    if (threadIdx.x == 0) out[j] = red[0] + (bias ? bias[j] : 0.f);
}

// u[j] = sum_i ce[i] * W1[i*IF + j]; one wave per j (W1 top half is 1MB -> L2)
__global__ __launch_bounds__(64) void u_kernel(const float* __restrict__ ce, const float* __restrict__ W1,
                                               float* __restrict__ u, int FD, int IF) {
    int j = blockIdx.x;
    int lane = threadIdx.x;
    float s = 0.f;
    for (int i = lane; i < FD; i += 64) s += ce[i] * W1[(size_t)i * IF + j];
    for (int off = 32; off > 0; off >>= 1) s += __shfl_down(s, off);
    if (lane == 0) u[j] = s;
}

// ---------------- conversion kernels ----------------

// vectorized pad+convert: float4 in -> bf16x4 out; icols%4==0, ocols%4==0
__global__ void pad_convert4(const float* __restrict__ in, int icols, int irows,
                             unsigned short* __restrict__ out, int ocols, int orows, int cpr) {
    int idx = blockIdx.x * blockDim.x + threadIdx.x;
    int row = idx / cpr;
    int c4 = (idx - row * cpr) * 4;
    if (row >= orows) return;
    float4 v = make_float4(0.f, 0.f, 0.f, 0.f);
    if (row < irows && c4 < icols)
        v = *(const float4*)(in + (size_t)row * icols + c4);
    u16x4_t o;
    o[0] = f2bf(v.x); o[1] = f2bf(v.y); o[2] = f2bf(v.z); o[3] = f2bf(v.w);
    *(u16x4_t*)(out + (size_t)row * ocols + c4) = o;
}

// out[n][k] = W[k][n] (bf16), zero-padded to [orows][ocols]
__global__ void transpose_pad(const float* __restrict__ W, int rows, int cols, int ldw,
                              unsigned short* __restrict__ out, int orows, int ocols) {
    __shared__ float tile[32][33];
    int k0 = blockIdx.x * 32, n0 = blockIdx.y * 32;
    int tx = threadIdx.x, ty = threadIdx.y;  // 32 x 8
    for (int i = 0; i < 32; i += 8) {
        int k = k0 + ty + i, n = n0 + tx;
        tile[ty + i][tx] = (k < rows && n < cols) ? W[(size_t)k * ldw + n] : 0.f;
    }
    __syncthreads();
    for (int i = 0; i < 32; i += 8) {
        int n = n0 + ty + i, k = k0 + tx;
        if (n < orows && k < ocols) out[(size_t)n * ocols + k] = f2bf(tile[tx][ty + i]);
    }
}

// ---------------- bf16 MFMA GEMM ----------------
// C[M][Cld] (bf16) = relu?( rowscale[r]*(A@B) + t[r]*u[c] + bias[c] )
// A: [M][Kp] bf16. Bt: [Np][Kp] bf16 (B column-major), Np = gridX*128. Kp % 32 == 0.
__global__ __launch_bounds__(256) void mfma_gemm(
    const unsigned short* __restrict__ A, const unsigned short* __restrict__ Bt,
    const float* __restrict__ bias, const float* __restrict__ rowscale,
    const float* __restrict__ tvec, const float* __restrict__ uvec,
    unsigned short* __restrict__ C, int M, int Nn, int Kp, int Cld, int relu) {
    __shared__ unsigned short As[128 * 32];
    __shared__ unsigned short Bs[128 * 32];
    int tid = threadIdx.x;
    int lane = tid & 63;
    int wave = tid >> 6;
    int wm = wave >> 1, wn = wave & 1;  // 2x2 waves, each 64x64
    int lg = lane >> 4, lt = lane & 15;
    int row0 = blockIdx.y * 128, col0 = blockIdx.x * 128;

    f32x4_t acc[4][4] = {};

    int nk = Kp >> 5;
    for (int kp = 0; kp < nk; kp++) {
        int k0 = kp << 5;
#pragma unroll
        for (int i = 0; i < 2; i++) {
            int cid = tid + i * 256;
            int r = cid >> 2, c = cid & 3;
            int sw = c ^ ((r >> 1) & 3);
            int4 av = make_int4(0, 0, 0, 0);
            int grA = row0 + r;
            if (grA < M) av = *(const int4*)(A + (size_t)grA * Kp + k0 + (c << 3));
            *(int4*)(As + r * 32 + sw * 8) = av;
            int4 bv = *(const int4*)(Bt + (size_t)(col0 + r) * Kp + k0 + (c << 3));
            *(int4*)(Bs + r * 32 + sw * 8) = bv;
        }
        __syncthreads();
        bf16x8_t af[4], bfr[4];
#pragma unroll
        for (int mi = 0; mi < 4; mi++) {
            int r = wm * 64 + mi * 16 + lt;
            int sw = lg ^ ((r >> 1) & 3);
            af[mi] = *(const bf16x8_t*)(As + r * 32 + sw * 8);
        }
#pragma unroll
        for (int ni = 0; ni < 4; ni++) {
            int r = wn * 64 + ni * 16 + lt;
            int sw = lg ^ ((r >> 1) & 3);
            bfr[ni] = *(const bf16x8_t*)(Bs + r * 32 + sw * 8);
        }
#pragma unroll
        for (int mi = 0; mi < 4; mi++)
#pragma unroll
            for (int ni = 0; ni < 4; ni++)
                acc[mi][ni] = __builtin_amdgcn_mfma_f32_16x16x32_bf16(af[mi], bfr[ni], acc[mi][ni], 0, 0, 0);
        __syncthreads();
    }

#pragma unroll
    for (int mi = 0; mi < 4; mi++) {
#pragma unroll
        for (int r = 0; r < 4; r++) {
            int row = row0 + wm * 64 + mi * 16 + lg * 4 + r;
            if (row >= M) continue;
            float rs = rowscale ? rowscale[row] : 1.f;
            float tvr = tvec ? tvec[row] : 0.f;
#pragma unroll
            for (int ni = 0; ni < 4; ni++) {
                int colb = col0 + wn * 64 + ni * 16 + lt;
                float v = 0.f;
                if (colb < Nn) {
                    v = acc[mi][ni][r] * rs;
                    if (bias) v += bias[colb];
                    if (tvec) v += tvr * uvec[colb];
                    if (relu) v = fmaxf(v, 0.f);
                }
                C[(size_t)row * Cld + colb] = f2bf(v);
            }
        }
    }
}

// ---------------- SpMM (CSR gather, bf16) ----------------
// Fp=512: two waves per node (256 cols each), 4-edge unroll
__global__ __launch_bounds__(256) void spmm_bf16_512(
    const int* __restrict__ rp, const int* __restrict__ col, const float* __restrict__ ns,
    const unsigned short* __restrict__ X, unsigned short* __restrict__ Y, int n) {
    int w = blockIdx.x * 4 + (threadIdx.x >> 6);
    int node = w >> 1, half = w & 1;
    if (node >= n) return;
    int lane = threadIdx.x & 63;
    int off = half * 256 + lane * 4;
    const unsigned short* Xo = X + off;
    int beg = rp[node], end = rp[node + 1];
    float a0 = 0.f, a1 = 0.f, a2 = 0.f, a3 = 0.f;
    int e = beg;
    for (; e + 3 < end; e += 4) {
        int s0 = col[e], s1 = col[e + 1], s2 = col[e + 2], s3 = col[e + 3];
        float w0 = ns[s0], w1 = ns[s1], w2 = ns[s2], w3 = ns[s3];
        u16x4_t v0 = *(const u16x4_t*)(Xo + (size_t)s0 * 512);
        u16x4_t v1 = *(const u16x4_t*)(Xo + (size_t)s1 * 512);
        u16x4_t v2 = *(const u16x4_t*)(Xo + (size_t)s2 * 512);
        u16x4_t v3 = *(const u16x4_t*)(Xo + (size_t)s3 * 512);
        a0 += w0 * bf2f(v0[0]) + w1 * bf2f(v1[0]) + w2 * bf2f(v2[0]) + w3 * bf2f(v3[0]);
        a1 += w0 * bf2f(v0[1]) + w1 * bf2f(v1[1]) + w2 * bf2f(v2[1]) + w3 * bf2f(v3[1]);
        a2 += w0 * bf2f(v0[2]) + w1 * bf2f(v1[2]) + w2 * bf2f(v2[2]) + w3 * bf2f(v3[2]);
        a3 += w0 * bf2f(v0[3]) + w1 * bf2f(v1[3]) + w2 * bf2f(v2[3]) + w3 * bf2f(v3[3]);
    }
    for (; e < end; e++) {
        int s0 = col[e];
        float w0 = ns[s0];
        u16x4_t v0 = *(const u16x4_t*)(Xo + (size_t)s0 * 512);
        a0 += w0 * bf2f(v0[0]); a1 += w0 * bf2f(v0[1]);
        a2 += w0 * bf2f(v0[2]); a3 += w0 * bf2f(v0[3]);
    }
    u16x4_t o;
    o[0] = f2bf(a0); o[1] = f2bf(a1); o[2] = f2bf(a2); o[3] = f2bf(a3);
    *(u16x4_t*)(Y + (size_t)node * 512 + off) = o;
}

// Fp=256: one wave per node, 4-edge unroll
__global__ __launch_bounds__(256) void spmm_bf16_256(
    const int* __restrict__ rp, const int* __restrict__ col, const float* __restrict__ ns,
    const unsigned short* __restrict__ X, unsigned short* __restrict__ Y, int n) {
    int node = blockIdx.x * 4 + (threadIdx.x >> 6);
    if (node >= n) return;
    int lane = threadIdx.x & 63;
    const unsigned short* Xo = X + lane * 4;
    int beg = rp[node], end = rp[node + 1];
    float a0 = 0.f, a1 = 0.f, a2 = 0.f, a3 = 0.f;
    int e = beg;
    for (; e + 3 < end; e += 4) {
        int s0 = col[e], s1 = col[e + 1], s2 = col[e + 2], s3 = col[e + 3];
        float w0 = ns[s0], w1 = ns[s1], w2 = ns[s2], w3 = ns[s3];
        u16x4_t v0 = *(const u16x4_t*)(Xo + (size_t)s0 * 256);
        u16x4_t v1 = *(const u16x4_t*)(Xo + (size_t)s1 * 256);
        u16x4_t v2 = *(const u16x4_t*)(Xo + (size_t)s2 * 256);
        u16x4_t v3 = *(const u16x4_t*)(Xo + (size_t)s3 * 256);
        a0 += w0 * bf2f(v0[0]) + w1 * bf2f(v1[0]) + w2 * bf2f(v2[0]) + w3 * bf2f(v3[0]);
        a1 += w0 * bf2f(v0[1]) + w1 * bf2f(v1[1]) + w2 * bf2f(v2[1]) + w3 * bf2f(v3[1]);
        a2 += w0 * bf2f(v0[2]) + w1 * bf2f(v1[2]) + w2 * bf2f(v2[2]) + w3 * bf2f(v3[2]);
        a3 += w0 * bf2f(v0[3]) + w1 * bf2f(v1[3]) + w2 * bf2f(v2[3]) + w3 * bf2f(v3[3]);
    }
    for (; e < end; e++) {
        int s0 = col[e];
        float w0 = ns[s0];
        u16x4_t v0 = *(const u16x4_t*)(Xo + (size_t)s0 * 256);
        a0 += w0 * bf2f(v0[0]); a1 += w0 * bf2f(v0[1]);
        a2 += w0 * bf2f(v0[2]); a3 += w0 * bf2f(v0[3]);
    }
    u16x4_t o;
    o[0] = f2bf(a0); o[1] = f2bf(a1); o[2] = f2bf(a2); o[3] = f2bf(a3);
    *(u16x4_t*)(Y + (size_t)node * 256 + lane * 4) = o;
}

// ---------------- z path ----------------

__global__ void gemv_col_bf(const unsigned short* __restrict__ X, const float* __restrict__ w,
                            float* __restrict__ z, int n, int K, int ld) {
    int g = threadIdx.x >> 6, lane = threadIdx.x & 63;
    int node = blockIdx.x * 4 + g;
    if (node >= n) return;
    const unsigned short* xr = X + (size_t)node * ld;
    float s = 0.f;
    for (int k = lane; k < K; k += 64) s += bf2f(xr[k]) * w[k];
    for (int off = 32; off > 0; off >>= 1) s += __shfl_down(s, off);
    if (lane == 0) z[node] = s;
}

// o[d] = relu(nd[d]*sum_e ns[col[e]]*z[col[e]] + b3)  (wave per node)
__global__ __launch_bounds__(256) void z_gather(const int* __restrict__ rp, const int* __restrict__ col,
                                                const float* __restrict__ ns, const float* __restrict__ z,
                                                const float* __restrict__ nd, const float* __restrict__ b3,
                                                float* __restrict__ o, int n) {
    int d = blockIdx.x * 4 + (threadIdx.x >> 6);
    if (d >= n) return;
    int lane = threadIdx.x & 63;
    int beg = rp[d], end = rp[d + 1];
    float acc = 0.f;
    for (int e = beg + lane; e < end; e += 64) {
        int s = col[e];
        acc += ns[s] * z[s];
    }
    for (int off = 32; off > 0; off >>= 1) acc += __shfl_down(acc, off);
    if (lane == 0) o[d] = fmaxf(nd[d] * acc + b3[0], 0.f);
}

// ---------------- launch ----------------

extern "C" void kernel_launch(void* const* d_in, const int* in_sizes, int n_in,
                              void* d_out, int out_size, void* d_ws, size_t ws_size,
                              hipStream_t stream) {
    const float* class_embed = (const float*)d_in[0];
    const float* all_glove   = (const float*)d_in[1];
    const float* W_word = (const float*)d_in[2];
    const float* b_word = (const float*)d_in[3];
    const float* W_img  = (const float*)d_in[4];
    const float* b_img  = (const float*)d_in[5];
    const float* W1 = (const float*)d_in[6];
    const float* b1 = (const float*)d_in[7];
    const float* W2 = (const float*)d_in[8];
    const float* b2 = (const float*)d_in[9];
    const float* W3 = (const float*)d_in[10];
    const float* b3 = (const float*)d_in[11];
    const float* W_fin = (const float*)d_in[12];
    const float* b_fin = (const float*)d_in[13];
    const int* src = (const int*)d_in[14];
    const int* dst = (const int*)d_in[15];

    const int N   = in_sizes[0];
    const int GLV = in_sizes[1] / N;   // 300
    const int FD  = in_sizes[5];       // 254
    const int IF  = in_sizes[7];       // 508
    const int E   = in_sizes[14];

    const int GLVp = 320;
    const int FDp  = 256;
    const int IFp  = 512;

    char* base = (char*)d_ws;
    size_t off = 0;
    auto alloc = [&](size_t bytes) -> void* {
        void* p = base + off;
        off = (off + bytes + 255) & ~(size_t)255;
        return p;
    };

    float* ns  = (float*)alloc((size_t)N * 4);
    float* nd  = (float*)alloc((size_t)N * 4);
    int* fill  = (int*)alloc((size_t)N * 4);
    size_t zero_bytes = (size_t)((char*)(fill + N) - (char*)ns);
    float* tv  = (float*)alloc((size_t)N * 4);
    float* ce  = (float*)alloc((size_t)FD * 4);
    float* u   = (float*)alloc((size_t)IF * 4);
    float* z   = (float*)alloc((size_t)N * 4);
    float* ov  = (float*)alloc((size_t)N * 4);
    int* rp    = (int*)alloc((size_t)(N + 1) * 4);
    int* bsum  = (int*)alloc(64 * 4);
    int* col   = (int*)alloc((size_t)E * 4);
    unsigned short* WwP  = (unsigned short*)alloc((size_t)FDp * GLVp * 2);
    unsigned short* W1hT = (unsigned short*)alloc((size_t)IFp * FDp * 2);
    unsigned short* W2T  = (unsigned short*)alloc((size_t)IFp * IFp * 2);
    unsigned short* glove_bf = (unsigned short*)alloc((size_t)N * GLVp * 2);
    unsigned short* we       = (unsigned short*)alloc((size_t)N * FDp * 2);
    unsigned short* h12      = (unsigned short*)alloc((size_t)N * IFp * 2);
    unsigned short* aggwe = glove_bf;
    unsigned short* agg2  = glove_bf;
    unsigned short* h1 = h12;
    unsigned short* h2 = h12;

    hipMemsetAsync(ns, 0, zero_bytes, stream);

    int gE = (E + TPB - 1) / TPB;
    int gN = (N + TPB - 1) / TPB;
    int nb = (N + 1023) / 1024;

    // CSR build + norms
    deg_kernel<<<gE, TPB, 0, stream>>>(src, dst, ns, nd, E);
    scan1<<<nb, 1024, 0, stream>>>(nd, rp, bsum, N);
    scan2<<<1, 64, 0, stream>>>(bsum, nb);
    scan3<<<nb, 1024, 0, stream>>>(rp, bsum, N);
    norm_kernel<<<gN, TPB, 0, stream>>>(ns, nd, N);
    scatter_kernel<<<gE, TPB, 0, stream>>>(src, dst, rp, fill, col, E);
    st_kernel<<<(N + 3) / 4, 256, 0, stream>>>(rp, col, ns, nd, tv, N);

    // ce = class_embed @ W_img.T + b_img ; u = ce @ W1[:FD, :]
    gemv_rows<<<FD, TPB, 0, stream>>>(class_embed, W_img, b_img, ce, N);
    u_kernel<<<IF, 64, 0, stream>>>(ce, W1, u, FD, IF);

    // conversions
    {
        int cpr = GLVp / 4;
        int tot = N * cpr;
        pad_convert4<<<(tot + 255) / 256, 256, 0, stream>>>(all_glove, GLV, N, glove_bf, GLVp, N, cpr);
        int tot2 = FDp * cpr;
        pad_convert4<<<(tot2 + 255) / 256, 256, 0, stream>>>(W_word, GLV, FD, WwP, GLVp, FDp, cpr);
    }
    {
        dim3 g(FDp / 32, IFp / 32);
        transpose_pad<<<g, dim3(32, 8), 0, stream>>>(W1 + (size_t)FD * IF, FD, IF, IF, W1hT, IFp, FDp);
    }
    {
        dim3 g(IFp / 32, IFp / 32);
        transpose_pad<<<g, dim3(32, 8), 0, stream>>>(W2, IF, IF, IF, W2T, IFp, IFp);
    }

    int mtiles = (N + 127) / 128;

    // we = all_glove @ W_word.T + b_word   [N][256] bf16
    {
        dim3 g(FDp / 128, mtiles);
        mfma_gemm<<<g, 256, 0, stream>>>(glove_bf, WwP, b_word, nullptr, nullptr, nullptr,
                                         we, N, FD, GLVp, FDp, 0);
    }
    // SpMM1: aggwe = sum ns[s]*we[s]   [N][256]
    spmm_bf16_256<<<(N + 3) / 4, 256, 0, stream>>>(rp, col, ns, we, aggwe, N);
    // h1 = relu(nd[r]*(aggwe @ W1[FD:,:]) + tv[r]*u[c] + b1)   [N][512]
    {
        dim3 g(IFp / 128, mtiles);
        mfma_gemm<<<g, 256, 0, stream>>>(aggwe, W1hT, b1, nd, tv, u, h1, N, IF, FDp, IFp, 1);
    }
    // SpMM2: agg2 = sum ns[s]*h1[s]   [N][512]
    spmm_bf16_512<<<(2 * N + 3) / 4, 256, 0, stream>>>(rp, col, ns, h1, agg2, N);
    // h2 = relu(nd[r]*(agg2 @ W2) + b2)   [N][512]
    {
        dim3 g(IFp / 128, mtiles);
        mfma_gemm<<<g, 256, 0, stream>>>(agg2, W2T, b2, nd, nullptr, nullptr, h2, N, IF, IFp, IFp, 1);
    }
    // z = h2 @ W3
    gemv_col_bf<<<(N + 3) / 4, 256, 0, stream>>>(h2, W3, z, N, IF, IFp);
    // o = relu(nd * gather(ns*z) + b3)
    z_gather<<<(N + 3) / 4, 256, 0, stream>>>(rp, col, ns, z, nd, b3, ov, N);
    // out = o @ W_fin.T + b_fin
    gemv_rows<<<FD, TPB, 0, stream>>>(ov, W_fin, b_fin, (float*)d_out, N);
}

// Round 5
// 427.999 us; speedup vs baseline: 6.3367x; 1.0041x over previous
//
#include <hip/hip_runtime.h>
#include <hip/hip_bf16.h>

#define TPB 256

typedef __attribute__((ext_vector_type(8))) short bf16x8_t;
typedef __attribute__((ext_vector_type(4))) float f32x4_t;
typedef __attribute__((ext_vector_type(8))) unsigned short u16x8_t;
typedef __attribute__((ext_vector_type(4))) unsigned short u16x4_t;

__device__ __forceinline__ float bf2f(unsigned short u) {
    return __uint_as_float(((unsigned)u) << 16);
}
__device__ __forceinline__ unsigned short f2bf(float f) {
    unsigned x = __float_as_uint(f);
    unsigned r = (x + 0x7fff + ((x >> 16) & 1)) >> 16;  // RNE
    return (unsigned short)r;
}

// ---------------- graph preprocessing ----------------

__global__ void deg_kernel(const int* __restrict__ src, const int* __restrict__ dst,
                           float* __restrict__ deg_out, float* __restrict__ deg_in, int E) {
    int i = blockIdx.x * blockDim.x + threadIdx.x;
    if (i < E) {
        atomicAdd(&deg_out[src[i]], 1.0f);
        atomicAdd(&deg_in[dst[i]], 1.0f);
    }
}

// phase 1: block-local inclusive scan of PADDED degrees -> rp[i+1]; block sum -> bsum[b]
__global__ __launch_bounds__(1024) void scan1(const float* __restrict__ deg,
                                              int* __restrict__ rp, int* __restrict__ bsum, int n) {
    __shared__ int buf[1024];
    int b = blockIdx.x;
    int i = b * 1024 + threadIdx.x;
    int v = (i < n) ? (((int)deg[i] + 7) & ~7) : 0;   // pad each list to multiple of 8
    buf[threadIdx.x] = v;
    __syncthreads();
    for (int off = 1; off < 1024; off <<= 1) {
        int t = (threadIdx.x >= off) ? buf[threadIdx.x - off] : 0;
        __syncthreads();
        buf[threadIdx.x] += t;
        __syncthreads();
    }
    if (i < n) rp[i + 1] = buf[threadIdx.x];
    if (threadIdx.x == 1023) bsum[b] = buf[1023];
    if (b == 0 && threadIdx.x == 0) rp[0] = 0;
}

// phase 2: single-wave inclusive scan of block sums (nb <= 64)
__global__ void scan2(int* __restrict__ bsum, int nb) {
    int lane = threadIdx.x;
    int v = (lane < nb) ? bsum[lane] : 0;
    for (int off = 1; off < 64; off <<= 1) {
        int t = __shfl_up(v, off);
        if (lane >= off) v += t;
    }
    if (lane < nb) bsum[lane] = v;
}

// phase 3: add previous-block inclusive sums
__global__ __launch_bounds__(1024) void scan3(int* __restrict__ rp, const int* __restrict__ bsum, int n) {
    int b = blockIdx.x;
    if (b == 0) return;
    int i = b * 1024 + threadIdx.x;
    if (i < n) rp[i + 1] += bsum[b - 1];
}

__global__ void norm_kernel(float* __restrict__ a, float* __restrict__ b, int n) {
    int i = blockIdx.x * blockDim.x + threadIdx.x;
    if (i < n) {
        float d = a[i]; a[i] = d > 0.f ? rsqrtf(d) : 0.f;
        float e = b[i]; b[i] = e > 0.f ? rsqrtf(e) : 0.f;
    }
}

// scatter edges into CSR buckets; payload = {src, ns[src]}
__global__ void scatter_kernel(const int* __restrict__ src, const int* __restrict__ dst,
                               const int* __restrict__ rp, int* __restrict__ fill,
                               const float* __restrict__ ns, int2* __restrict__ payload, int E) {
    int i = blockIdx.x * blockDim.x + threadIdx.x;
    if (i < E) {
        int d = dst[i];
        int s = src[i];
        int pos = rp[d] + atomicAdd(&fill[d], 1);
        payload[pos] = make_int2(s, __float_as_int(ns[s]));
    }
}

// t[d] = nd[d] * sum_e w_e   (padding has w=0)
__global__ __launch_bounds__(256) void st_kernel(const int* __restrict__ rp,
                                                 const int2* __restrict__ payload,
                                                 const float* __restrict__ nd,
                                                 float* __restrict__ tv, int n) {
    int d = blockIdx.x * 4 + (threadIdx.x >> 6);
    if (d >= n) return;
    int lane = threadIdx.x & 63;
    int beg = rp[d], end = rp[d + 1];
    float acc = 0.f;
    for (int e = beg + lane; e < end; e += 64) acc += __int_as_float(payload[e].y);
    for (int off = 32; off > 0; off >>= 1) acc += __shfl_down(acc, off);
    if (lane == 0) tv[d] = acc * nd[d];
}

// ---------------- small GEMV (fp32) ----------------

__global__ void gemv_rows(const float* __restrict__ vec, const float* __restrict__ Mat,
                          const float* __restrict__ bias, float* __restrict__ out, int n) {
    int j = blockIdx.x;
    const float* row = Mat + (size_t)j * n;
    float s = 0.f;
    for (int i = threadIdx.x; i < n; i += blockDim.x) s += vec[i] * row[i];
    __shared__ float red[TPB];
    red[threadIdx.x] = s;
    __syncthreads();
    for (int o = TPB / 2; o > 0; o >>= 1) {
        if (threadIdx.x < o) red[threadIdx.x] += red[threadIdx.x + o];
        __syncthreads();
    }
    if (threadIdx.x == 0) out[j] = red[0] + (bias ? bias[j] : 0.f);
}

// u[j] = sum_i ce[i] * W1[i*IF + j]; one wave per j
__global__ __launch_bounds__(64) void u_kernel(const float* __restrict__ ce, const float* __restrict__ W1,
                                               float* __restrict__ u, int FD, int IF) {
    int j = blockIdx.x;
    int lane = threadIdx.x;
    float s = 0.f;
    for (int i = lane; i < FD; i += 64) s += ce[i] * W1[(size_t)i * IF + j];
    for (int off = 32; off > 0; off >>= 1) s += __shfl_down(s, off);
    if (lane == 0) u[j] = s;
}

// ---------------- conversion kernels ----------------

__global__ void pad_convert4(const float* __restrict__ in, int icols, int irows,
                             unsigned short* __restrict__ out, int ocols, int orows, int cpr) {
    int idx = blockIdx.x * blockDim.x + threadIdx.x;
    int row = idx / cpr;
    int c4 = (idx - row * cpr) * 4;
    if (row >= orows) return;
    float4 v = make_float4(0.f, 0.f, 0.f, 0.f);
    if (row < irows && c4 < icols)
        v = *(const float4*)(in + (size_t)row * icols + c4);
    u16x4_t o;
    o[0] = f2bf(v.x); o[1] = f2bf(v.y); o[2] = f2bf(v.z); o[3] = f2bf(v.w);
    *(u16x4_t*)(out + (size_t)row * ocols + c4) = o;
}

__global__ void transpose_pad(const float* __restrict__ W, int rows, int cols, int ldw,
                              unsigned short* __restrict__ out, int orows, int ocols) {
    __shared__ float tile[32][33];
    int k0 = blockIdx.x * 32, n0 = blockIdx.y * 32;
    int tx = threadIdx.x, ty = threadIdx.y;  // 32 x 8
    for (int i = 0; i < 32; i += 8) {
        int k = k0 + ty + i, n = n0 + tx;
        tile[ty + i][tx] = (k < rows && n < cols) ? W[(size_t)k * ldw + n] : 0.f;
    }
    __syncthreads();
    for (int i = 0; i < 32; i += 8) {
        int n = n0 + ty + i, k = k0 + tx;
        if (n < orows && k < ocols) out[(size_t)n * ocols + k] = f2bf(tile[tx][ty + i]);
    }
}

// ---------------- bf16 MFMA GEMM ----------------
__global__ __launch_bounds__(256) void mfma_gemm(
    const unsigned short* __restrict__ A, const unsigned short* __restrict__ Bt,
    const float* __restrict__ bias, const float* __restrict__ rowscale,
    const float* __restrict__ tvec, const float* __restrict__ uvec,
    unsigned short* __restrict__ C, int M, int Nn, int Kp, int Cld, int relu) {
    __shared__ unsigned short As[128 * 32];
    __shared__ unsigned short Bs[128 * 32];
    int tid = threadIdx.x;
    int lane = tid & 63;
    int wave = tid >> 6;
    int wm = wave >> 1, wn = wave & 1;  // 2x2 waves, each 64x64
    int lg = lane >> 4, lt = lane & 15;
    int row0 = blockIdx.y * 128, col0 = blockIdx.x * 128;

    f32x4_t acc[4][4] = {};

    int nk = Kp >> 5;
    for (int kp = 0; kp < nk; kp++) {
        int k0 = kp << 5;
#pragma unroll
        for (int i = 0; i < 2; i++) {
            int cid = tid + i * 256;
            int r = cid >> 2, c = cid & 3;
            int sw = c ^ ((r >> 1) & 3);
            int4 av = make_int4(0, 0, 0, 0);
            int grA = row0 + r;
            if (grA < M) av = *(const int4*)(A + (size_t)grA * Kp + k0 + (c << 3));
            *(int4*)(As + r * 32 + sw * 8) = av;
            int4 bv = *(const int4*)(Bt + (size_t)(col0 + r) * Kp + k0 + (c << 3));
            *(int4*)(Bs + r * 32 + sw * 8) = bv;
        }
        __syncthreads();
        bf16x8_t af[4], bfr[4];
#pragma unroll
        for (int mi = 0; mi < 4; mi++) {
            int r = wm * 64 + mi * 16 + lt;
            int sw = lg ^ ((r >> 1) & 3);
            af[mi] = *(const bf16x8_t*)(As + r * 32 + sw * 8);
        }
#pragma unroll
        for (int ni = 0; ni < 4; ni++) {
            int r = wn * 64 + ni * 16 + lt;
            int sw = lg ^ ((r >> 1) & 3);
            bfr[ni] = *(const bf16x8_t*)(Bs + r * 32 + sw * 8);
        }
#pragma unroll
        for (int mi = 0; mi < 4; mi++)
#pragma unroll
            for (int ni = 0; ni < 4; ni++)
                acc[mi][ni] = __builtin_amdgcn_mfma_f32_16x16x32_bf16(af[mi], bfr[ni], acc[mi][ni], 0, 0, 0);
        __syncthreads();
    }

#pragma unroll
    for (int mi = 0; mi < 4; mi++) {
#pragma unroll
        for (int r = 0; r < 4; r++) {
            int row = row0 + wm * 64 + mi * 16 + lg * 4 + r;
            if (row >= M) continue;
            float rs = rowscale ? rowscale[row] : 1.f;
            float tvr = tvec ? tvec[row] : 0.f;
#pragma unroll
            for (int ni = 0; ni < 4; ni++) {
                int colb = col0 + wn * 64 + ni * 16 + lt;
                float v = 0.f;
                if (colb < Nn) {
                    v = acc[mi][ni][r] * rs;
                    if (bias) v += bias[colb];
                    if (tvec) v += tvr * uvec[colb];
                    if (relu) v = fmaxf(v, 0.f);
                }
                C[(size_t)row * Cld + colb] = f2bf(v);
            }
        }
    }
}

// ---------------- SpMM (CSR gather, payload, 8-edge unroll, tail-free) ----------------
// Fp=512: one wave per node, 16B/lane; padded lists (w=0) -> (end-beg)%8==0
__global__ __launch_bounds__(256) void spmm_bf16_512(
    const int* __restrict__ rp, const int2* __restrict__ payload,
    const unsigned short* __restrict__ X, unsigned short* __restrict__ Y, int n) {
    int node = blockIdx.x * 4 + (threadIdx.x >> 6);
    if (node >= n) return;
    int lane = threadIdx.x & 63;
    const unsigned short* Xo = X + lane * 8;
    int beg = rp[node], end = rp[node + 1];
    float acc[8] = {};
    for (int e = beg; e < end; e += 8) {
        int2 p[8];
#pragma unroll
        for (int j = 0; j < 8; j++) p[j] = payload[e + j];
        u16x8_t v[8];
#pragma unroll
        for (int j = 0; j < 8; j++) v[j] = *(const u16x8_t*)(Xo + (size_t)p[j].x * 512);
#pragma unroll
        for (int j = 0; j < 8; j++) {
            float w = __int_as_float(p[j].y);
#pragma unroll
            for (int c = 0; c < 8; c++) acc[c] += w * bf2f(v[j][c]);
        }
    }
    u16x8_t o;
#pragma unroll
    for (int c = 0; c < 8; c++) o[c] = f2bf(acc[c]);
    *(u16x8_t*)(Y + (size_t)node * 512 + lane * 8) = o;
}

// Fp=256: one wave per node, 8B/lane
__global__ __launch_bounds__(256) void spmm_bf16_256(
    const int* __restrict__ rp, const int2* __restrict__ payload,
    const unsigned short* __restrict__ X, unsigned short* __restrict__ Y, int n) {
    int node = blockIdx.x * 4 + (threadIdx.x >> 6);
    if (node >= n) return;
    int lane = threadIdx.x & 63;
    const unsigned short* Xo = X + lane * 4;
    int beg = rp[node], end = rp[node + 1];
    float acc[4] = {};
    for (int e = beg; e < end; e += 8) {
        int2 p[8];
#pragma unroll
        for (int j = 0; j < 8; j++) p[j] = payload[e + j];
        u16x4_t v[8];
#pragma unroll
        for (int j = 0; j < 8; j++) v[j] = *(const u16x4_t*)(Xo + (size_t)p[j].x * 256);
#pragma unroll
        for (int j = 0; j < 8; j++) {
            float w = __int_as_float(p[j].y);
#pragma unroll
            for (int c = 0; c < 4; c++) acc[c] += w * bf2f(v[j][c]);
        }
    }
    u16x4_t o;
#pragma unroll
    for (int c = 0; c < 4; c++) o[c] = f2bf(acc[c]);
    *(u16x4_t*)(Y + (size_t)node * 256 + lane * 4) = o;
}

// ---------------- z path ----------------

__global__ void gemv_col_bf(const unsigned short* __restrict__ X, const float* __restrict__ w,
                            float* __restrict__ z, int n, int K, int ld) {
    int g = threadIdx.x >> 6, lane = threadIdx.x & 63;
    int node = blockIdx.x * 4 + g;
    if (node >= n) return;
    const unsigned short* xr = X + (size_t)node * ld;
    float s = 0.f;
    for (int k = lane; k < K; k += 64) s += bf2f(xr[k]) * w[k];
    for (int off = 32; off > 0; off >>= 1) s += __shfl_down(s, off);
    if (lane == 0) z[node] = s;
}

// o[d] = relu(nd[d]*sum_e w_e*z[s_e] + b3)  (wave per node, payload)
__global__ __launch_bounds__(256) void z_gather(const int* __restrict__ rp,
                                                const int2* __restrict__ payload,
                                                const float* __restrict__ z,
                                                const float* __restrict__ nd, const float* __restrict__ b3,
                                                float* __restrict__ o, int n) {
    int d = blockIdx.x * 4 + (threadIdx.x >> 6);
    if (d >= n) return;
    int lane = threadIdx.x & 63;
    int beg = rp[d], end = rp[d + 1];
    float acc = 0.f;
    for (int e = beg + lane; e < end; e += 64) {
        int2 p = payload[e];
        acc += __int_as_float(p.y) * z[p.x];
    }
    for (int off = 32; off > 0; off >>= 1) acc += __shfl_down(acc, off);
    if (lane == 0) o[d] = fmaxf(nd[d] * acc + b3[0], 0.f);
}

// ---------------- launch ----------------

extern "C" void kernel_launch(void* const* d_in, const int* in_sizes, int n_in,
                              void* d_out, int out_size, void* d_ws, size_t ws_size,
                              hipStream_t stream) {
    const float* class_embed = (const float*)d_in[0];
    const float* all_glove   = (const float*)d_in[1];
    const float* W_word = (const float*)d_in[2];
    const float* b_word = (const float*)d_in[3];
    const float* W_img  = (const float*)d_in[4];
    const float* b_img  = (const float*)d_in[5];
    const float* W1 = (const float*)d_in[6];
    const float* b1 = (const float*)d_in[7];
    const float* W2 = (const float*)d_in[8];
    const float* b2 = (const float*)d_in[9];
    const float* W3 = (const float*)d_in[10];
    const float* b3 = (const float*)d_in[11];
    const float* W_fin = (const float*)d_in[12];
    const float* b_fin = (const float*)d_in[13];
    const int* src = (const int*)d_in[14];
    const int* dst = (const int*)d_in[15];

    const int N   = in_sizes[0];
    const int GLV = in_sizes[1] / N;   // 300
    const int FD  = in_sizes[5];       // 254
    const int IF  = in_sizes[7];       // 508
    const int E   = in_sizes[14];

    const int GLVp = 320;
    const int FDp  = 256;
    const int IFp  = 512;
    const int EP   = E + 8 * N;        // padded edge capacity

    char* base = (char*)d_ws;
    size_t off = 0;
    auto alloc = [&](size_t bytes) -> void* {
        void* p = base + off;
        off = (off + bytes + 255) & ~(size_t)255;
        return p;
    };

    float* ns  = (float*)alloc((size_t)N * 4);
    float* nd  = (float*)alloc((size_t)N * 4);
    int* fill  = (int*)alloc((size_t)N * 4);
    size_t zero_bytes = (size_t)((char*)(fill + N) - (char*)ns);
    float* tv  = (float*)alloc((size_t)N * 4);
    float* ce  = (float*)alloc((size_t)FD * 4);
    float* u   = (float*)alloc((size_t)IF * 4);
    float* z   = (float*)alloc((size_t)N * 4);
    float* ov  = (float*)alloc((size_t)N * 4);
    int* rp    = (int*)alloc((size_t)(N + 1) * 4);
    int* bsum  = (int*)alloc(64 * 4);
    int2* payload = (int2*)alloc((size_t)EP * 8);
    unsigned short* WwP  = (unsigned short*)alloc((size_t)FDp * GLVp * 2);
    unsigned short* W1hT = (unsigned short*)alloc((size_t)IFp * FDp * 2);
    unsigned short* W2T  = (unsigned short*)alloc((size_t)IFp * IFp * 2);
    unsigned short* glove_bf = (unsigned short*)alloc((size_t)N * GLVp * 2);
    unsigned short* we       = (unsigned short*)alloc((size_t)N * FDp * 2);
    unsigned short* h12      = (unsigned short*)alloc((size_t)N * IFp * 2);
    unsigned short* aggwe = glove_bf;
    unsigned short* agg2  = glove_bf;
    unsigned short* h1 = h12;
    unsigned short* h2 = h12;

    hipMemsetAsync(ns, 0, zero_bytes, stream);
    hipMemsetAsync(payload, 0, (size_t)EP * 8, stream);  // padding edges: {s=0, w=0}

    int gE = (E + TPB - 1) / TPB;
    int gN = (N + TPB - 1) / TPB;
    int nb = (N + 1023) / 1024;

    // CSR build + norms
    deg_kernel<<<gE, TPB, 0, stream>>>(src, dst, ns, nd, E);
    scan1<<<nb, 1024, 0, stream>>>(nd, rp, bsum, N);
    scan2<<<1, 64, 0, stream>>>(bsum, nb);
    scan3<<<nb, 1024, 0, stream>>>(rp, bsum, N);
    norm_kernel<<<gN, TPB, 0, stream>>>(ns, nd, N);
    scatter_kernel<<<gE, TPB, 0, stream>>>(src, dst, rp, fill, ns, payload, E);
    st_kernel<<<(N + 3) / 4, 256, 0, stream>>>(rp, payload, nd, tv, N);

    // ce = class_embed @ W_img.T + b_img ; u = ce @ W1[:FD, :]
    gemv_rows<<<FD, TPB, 0, stream>>>(class_embed, W_img, b_img, ce, N);
    u_kernel<<<IF, 64, 0, stream>>>(ce, W1, u, FD, IF);

    // conversions
    {
        int cpr = GLVp / 4;
        int tot = N * cpr;
        pad_convert4<<<(tot + 255) / 256, 256, 0, stream>>>(all_glove, GLV, N, glove_bf, GLVp, N, cpr);
        int tot2 = FDp * cpr;
        pad_convert4<<<(tot2 + 255) / 256, 256, 0, stream>>>(W_word, GLV, FD, WwP, GLVp, FDp, cpr);
    }
    {
        dim3 g(FDp / 32, IFp / 32);
        transpose_pad<<<g, dim3(32, 8), 0, stream>>>(W1 + (size_t)FD * IF, FD, IF, IF, W1hT, IFp, FDp);
    }
    {
        dim3 g(IFp / 32, IFp / 32);
        transpose_pad<<<g, dim3(32, 8), 0, stream>>>(W2, IF, IF, IF, W2T, IFp, IFp);
    }

    int mtiles = (N + 127) / 128;

    // we = all_glove @ W_word.T + b_word   [N][256] bf16
    {
        dim3 g(FDp / 128, mtiles);
        mfma_gemm<<<g, 256, 0, stream>>>(glove_bf, WwP, b_word, nullptr, nullptr, nullptr,
                                         we, N, FD, GLVp, FDp, 0);
    }
    // SpMM1: aggwe = sum w*we[s]   [N][256]
    spmm_bf16_256<<<(N + 3) / 4, 256, 0, stream>>>(rp, payload, we, aggwe, N);
    // h1 = relu(nd[r]*(aggwe @ W1[FD:,:]) + tv[r]*u[c] + b1)   [N][512]
    {
        dim3 g(IFp / 128, mtiles);
        mfma_gemm<<<g, 256, 0, stream>>>(aggwe, W1hT, b1, nd, tv, u, h1, N, IF, FDp, IFp, 1);
    }
    // SpMM2: agg2 = sum w*h1[s]   [N][512]
    spmm_bf16_512<<<(N + 3) / 4, 256, 0, stream>>>(rp, payload, h1, agg2, N);
    // h2 = relu(nd[r]*(agg2 @ W2) + b2)   [N][512]
    {
        dim3 g(IFp / 128, mtiles);
        mfma_gemm<<<g, 256, 0, stream>>>(agg2, W2T, b2, nd, nullptr, nullptr, h2, N, IF, IFp, IFp, 1);
    }
    // z = h2 @ W3
    gemv_col_bf<<<(N + 3) / 4, 256, 0, stream>>>(h2, W3, z, N, IF, IFp);
    // o = relu(nd * gather(w*z) + b3)
    z_gather<<<(N + 3) / 4, 256, 0, stream>>>(rp, payload, z, nd, b3, ov, N);
    // out = o @ W_fin.T + b_fin
    gemv_rows<<<FD, TPB, 0, stream>>>(ov, W_fin, b_fin, (float*)d_out, N);
}

// Round 6
// 427.961 us; speedup vs baseline: 6.3372x; 1.0001x over previous
//
#include <hip/hip_runtime.h>
#include <hip/hip_bf16.h>

#define TPB 256

typedef __attribute__((ext_vector_type(8))) short bf16x8_t;
typedef __attribute__((ext_vector_type(4))) float f32x4_t;
typedef __attribute__((ext_vector_type(8))) unsigned short u16x8_t;
typedef __attribute__((ext_vector_type(4))) unsigned short u16x4_t;

__device__ __forceinline__ float bf2f(unsigned short u) {
    return __uint_as_float(((unsigned)u) << 16);
}
__device__ __forceinline__ unsigned short f2bf(float f) {
    unsigned x = __float_as_uint(f);
    unsigned r = (x + 0x7fff + ((x >> 16) & 1)) >> 16;  // RNE
    return (unsigned short)r;
}

// ---------------- graph preprocessing ----------------

__global__ void deg_kernel(const int* __restrict__ src, const int* __restrict__ dst,
                           float* __restrict__ deg_out, float* __restrict__ deg_in, int E) {
    int i = blockIdx.x * blockDim.x + threadIdx.x;
    if (i < E) {
        atomicAdd(&deg_out[src[i]], 1.0f);
        atomicAdd(&deg_in[dst[i]], 1.0f);
    }
}

// phase 1: block-local inclusive scan of PADDED degrees -> rp[i+1]; block sum -> bsum[b]
__global__ __launch_bounds__(1024) void scan1(const float* __restrict__ deg,
                                              int* __restrict__ rp, int* __restrict__ bsum, int n) {
    __shared__ int buf[1024];
    int b = blockIdx.x;
    int i = b * 1024 + threadIdx.x;
    int v = (i < n) ? (((int)deg[i] + 7) & ~7) : 0;   // pad each list to multiple of 8
    buf[threadIdx.x] = v;
    __syncthreads();
    for (int off = 1; off < 1024; off <<= 1) {
        int t = (threadIdx.x >= off) ? buf[threadIdx.x - off] : 0;
        __syncthreads();
        buf[threadIdx.x] += t;
        __syncthreads();
    }
    if (i < n) rp[i + 1] = buf[threadIdx.x];
    if (threadIdx.x == 1023) bsum[b] = buf[1023];
    if (b == 0 && threadIdx.x == 0) rp[0] = 0;
}

__global__ void scan2(int* __restrict__ bsum, int nb) {
    int lane = threadIdx.x;
    int v = (lane < nb) ? bsum[lane] : 0;
    for (int off = 1; off < 64; off <<= 1) {
        int t = __shfl_up(v, off);
        if (lane >= off) v += t;
    }
    if (lane < nb) bsum[lane] = v;
}

__global__ __launch_bounds__(1024) void scan3(int* __restrict__ rp, const int* __restrict__ bsum, int n) {
    int b = blockIdx.x;
    if (b == 0) return;
    int i = b * 1024 + threadIdx.x;
    if (i < n) rp[i + 1] += bsum[b - 1];
}

__global__ void norm_kernel(float* __restrict__ a, float* __restrict__ b, int n) {
    int i = blockIdx.x * blockDim.x + threadIdx.x;
    if (i < n) {
        float d = a[i]; a[i] = d > 0.f ? rsqrtf(d) : 0.f;
        float e = b[i]; b[i] = e > 0.f ? rsqrtf(e) : 0.f;
    }
}

// scatter edges into CSR buckets; payload = {src, ns[src]}
__global__ void scatter_kernel(const int* __restrict__ src, const int* __restrict__ dst,
                               const int* __restrict__ rp, int* __restrict__ fill,
                               const float* __restrict__ ns, int2* __restrict__ payload, int E) {
    int i = blockIdx.x * blockDim.x + threadIdx.x;
    if (i < E) {
        int d = dst[i];
        int s = src[i];
        int pos = rp[d] + atomicAdd(&fill[d], 1);
        payload[pos] = make_int2(s, __float_as_int(ns[s]));
    }
}

// t[d] = nd[d] * sum_e w_e   (padding has w=0)
__global__ __launch_bounds__(256) void st_kernel(const int* __restrict__ rp,
                                                 const int2* __restrict__ payload,
                                                 const float* __restrict__ nd,
                                                 float* __restrict__ tv, int n) {
    int d = blockIdx.x * 4 + (threadIdx.x >> 6);
    if (d >= n) return;
    int lane = threadIdx.x & 63;
    int beg = rp[d], end = rp[d + 1];
    float acc = 0.f;
    for (int e = beg + lane; e < end; e += 64) acc += __int_as_float(payload[e].y);
    for (int off = 32; off > 0; off >>= 1) acc += __shfl_down(acc, off);
    if (lane == 0) tv[d] = acc * nd[d];
}

// ---------------- small GEMV (fp32) ----------------

__global__ void gemv_rows(const float* __restrict__ vec, const float* __restrict__ Mat,
                          const float* __restrict__ bias, float* __restrict__ out, int n) {
    int j = blockIdx.x;
    const float* row = Mat + (size_t)j * n;
    float s = 0.f;
    for (int i = threadIdx.x; i < n; i += blockDim.x) s += vec[i] * row[i];
    __shared__ float red[TPB];
    red[threadIdx.x] = s;
    __syncthreads();
    for (int o = TPB / 2; o > 0; o >>= 1) {
        if (threadIdx.x < o) red[threadIdx.x] += red[threadIdx.x + o];
        __syncthreads();
    }
    if (threadIdx.x == 0) out[j] = red[0] + (bias ? bias[j] : 0.f);
}

__global__ __launch_bounds__(64) void u_kernel(const float* __restrict__ ce, const float* __restrict__ W1,
                                               float* __restrict__ u, int FD, int IF) {
    int j = blockIdx.x;
    int lane = threadIdx.x;
    float s = 0.f;
    for (int i = lane; i < FD; i += 64) s += ce[i] * W1[(size_t)i * IF + j];
    for (int off = 32; off > 0; off >>= 1) s += __shfl_down(s, off);
    if (lane == 0) u[j] = s;
}

// ---------------- conversion kernels ----------------

__global__ void pad_convert4(const float* __restrict__ in, int icols, int irows,
                             unsigned short* __restrict__ out, int ocols, int orows, int cpr) {
    int idx = blockIdx.x * blockDim.x + threadIdx.x;
    int row = idx / cpr;
    int c4 = (idx - row * cpr) * 4;
    if (row >= orows) return;
    float4 v = make_float4(0.f, 0.f, 0.f, 0.f);
    if (row < irows && c4 < icols)
        v = *(const float4*)(in + (size_t)row * icols + c4);
    u16x4_t o;
    o[0] = f2bf(v.x); o[1] = f2bf(v.y); o[2] = f2bf(v.z); o[3] = f2bf(v.w);
    *(u16x4_t*)(out + (size_t)row * ocols + c4) = o;
}

__global__ void transpose_pad(const float* __restrict__ W, int rows, int cols, int ldw,
                              unsigned short* __restrict__ out, int orows, int ocols) {
    __shared__ float tile[32][33];
    int k0 = blockIdx.x * 32, n0 = blockIdx.y * 32;
    int tx = threadIdx.x, ty = threadIdx.y;  // 32 x 8
    for (int i = 0; i < 32; i += 8) {
        int k = k0 + ty + i, n = n0 + tx;
        tile[ty + i][tx] = (k < rows && n < cols) ? W[(size_t)k * ldw + n] : 0.f;
    }
    __syncthreads();
    for (int i = 0; i < 32; i += 8) {
        int n = n0 + ty + i, k = k0 + tx;
        if (n < orows && k < ocols) out[(size_t)n * ocols + k] = f2bf(tile[tx][ty + i]);
    }
}

// ---------------- bf16 MFMA GEMM ----------------
// Optional fused z-epilogue: zout[row] += sum_col relu'd(v[row,col]) * w3[col] (fp32 atomics).
// If C == nullptr the bf16 tile is not written (pure z computation).
__global__ __launch_bounds__(256) void mfma_gemm(
    const unsigned short* __restrict__ A, const unsigned short* __restrict__ Bt,
    const float* __restrict__ bias, const float* __restrict__ rowscale,
    const float* __restrict__ tvec, const float* __restrict__ uvec,
    const float* __restrict__ w3, float* __restrict__ zout,
    unsigned short* __restrict__ C, int M, int Nn, int Kp, int Cld, int relu) {
    __shared__ unsigned short As[128 * 32];
    __shared__ unsigned short Bs[128 * 32];
    int tid = threadIdx.x;
    int lane = tid & 63;
    int wave = tid >> 6;
    int wm = wave >> 1, wn = wave & 1;  // 2x2 waves, each 64x64
    int lg = lane >> 4, lt = lane & 15;
    int row0 = blockIdx.y * 128, col0 = blockIdx.x * 128;

    f32x4_t acc[4][4] = {};

    int nk = Kp >> 5;
    for (int kp = 0; kp < nk; kp++) {
        int k0 = kp << 5;
#pragma unroll
        for (int i = 0; i < 2; i++) {
            int cid = tid + i * 256;
            int r = cid >> 2, c = cid & 3;
            int sw = c ^ ((r >> 1) & 3);
            int4 av = make_int4(0, 0, 0, 0);
            int grA = row0 + r;
            if (grA < M) av = *(const int4*)(A + (size_t)grA * Kp + k0 + (c << 3));
            *(int4*)(As + r * 32 + sw * 8) = av;
            int4 bv = *(const int4*)(Bt + (size_t)(col0 + r) * Kp + k0 + (c << 3));
            *(int4*)(Bs + r * 32 + sw * 8) = bv;
        }
        __syncthreads();
        bf16x8_t af[4], bfr[4];
#pragma unroll
        for (int mi = 0; mi < 4; mi++) {
            int r = wm * 64 + mi * 16 + lt;
            int sw = lg ^ ((r >> 1) & 3);
            af[mi] = *(const bf16x8_t*)(As + r * 32 + sw * 8);
        }
#pragma unroll
        for (int ni = 0; ni < 4; ni++) {
            int r = wn * 64 + ni * 16 + lt;
            int sw = lg ^ ((r >> 1) & 3);
            bfr[ni] = *(const bf16x8_t*)(Bs + r * 32 + sw * 8);
        }
#pragma unroll
        for (int mi = 0; mi < 4; mi++)
#pragma unroll
            for (int ni = 0; ni < 4; ni++)
                acc[mi][ni] = __builtin_amdgcn_mfma_f32_16x16x32_bf16(af[mi], bfr[ni], acc[mi][ni], 0, 0, 0);
        __syncthreads();
    }

#pragma unroll
    for (int mi = 0; mi < 4; mi++) {
#pragma unroll
        for (int r = 0; r < 4; r++) {
            int row = row0 + wm * 64 + mi * 16 + lg * 4 + r;
            if (row >= M) continue;
            float rs = rowscale ? rowscale[row] : 1.f;
            float tvr = tvec ? tvec[row] : 0.f;
            float zp = 0.f;
#pragma unroll
            for (int ni = 0; ni < 4; ni++) {
                int colb = col0 + wn * 64 + ni * 16 + lt;
                float v = 0.f;
                if (colb < Nn) {
                    v = acc[mi][ni][r] * rs;
                    if (bias) v += bias[colb];
                    if (tvec) v += tvr * uvec[colb];
                    if (relu) v = fmaxf(v, 0.f);
                    if (w3) zp += v * w3[colb];
                }
                if (C) C[(size_t)row * Cld + colb] = f2bf(v);
            }
            if (w3) {
                // reduce zp across the 16 lt-lanes (row is uniform within the group)
                zp += __shfl_xor(zp, 1);
                zp += __shfl_xor(zp, 2);
                zp += __shfl_xor(zp, 4);
                zp += __shfl_xor(zp, 8);
                if (lt == 0) atomicAdd(&zout[row], zp);
            }
        }
    }
}

// ---------------- SpMM (CSR gather, payload, 8-edge unroll, tail-free) ----------------
// Columns [c0, c0+256) of X (row stride ld); one wave per node, u16x4/lane.
__global__ __launch_bounds__(256) void spmm_bf16_cols(
    const int* __restrict__ rp, const int2* __restrict__ payload,
    const unsigned short* __restrict__ X, unsigned short* __restrict__ Y,
    int n, int ld, int c0) {
    int node = blockIdx.x * 4 + (threadIdx.x >> 6);
    if (node >= n) return;
    int lane = threadIdx.x & 63;
    const unsigned short* Xo = X + c0 + lane * 4;
    int beg = rp[node], end = rp[node + 1];
    float acc[4] = {};
    for (int e = beg; e < end; e += 8) {
        int2 p[8];
#pragma unroll
        for (int j = 0; j < 8; j++) p[j] = payload[e + j];
        u16x4_t v[8];
#pragma unroll
        for (int j = 0; j < 8; j++) v[j] = *(const u16x4_t*)(Xo + (size_t)p[j].x * ld);
#pragma unroll
        for (int j = 0; j < 8; j++) {
            float w = __int_as_float(p[j].y);
#pragma unroll
            for (int c = 0; c < 4; c++) acc[c] += w * bf2f(v[j][c]);
        }
    }
    u16x4_t o;
#pragma unroll
    for (int c = 0; c < 4; c++) o[c] = f2bf(acc[c]);
    *(u16x4_t*)(Y + (size_t)node * ld + c0 + lane * 4) = o;
}

// ---------------- z path ----------------

// o[d] = relu(nd[d]*sum_e w_e*z[s_e] + b3)  (wave per node, payload)
__global__ __launch_bounds__(256) void z_gather(const int* __restrict__ rp,
                                                const int2* __restrict__ payload,
                                                const float* __restrict__ z,
                                                const float* __restrict__ nd, const float* __restrict__ b3,
                                                float* __restrict__ o, int n) {
    int d = blockIdx.x * 4 + (threadIdx.x >> 6);
    if (d >= n) return;
    int lane = threadIdx.x & 63;
    int beg = rp[d], end = rp[d + 1];
    float acc = 0.f;
    for (int e = beg + lane; e < end; e += 64) {
        int2 p = payload[e];
        acc += __int_as_float(p.y) * z[p.x];
    }
    for (int off = 32; off > 0; off >>= 1) acc += __shfl_down(acc, off);
    if (lane == 0) o[d] = fmaxf(nd[d] * acc + b3[0], 0.f);
}

// ---------------- launch ----------------

extern "C" void kernel_launch(void* const* d_in, const int* in_sizes, int n_in,
                              void* d_out, int out_size, void* d_ws, size_t ws_size,
                              hipStream_t stream) {
    const float* class_embed = (const float*)d_in[0];
    const float* all_glove   = (const float*)d_in[1];
    const float* W_word = (const float*)d_in[2];
    const float* b_word = (const float*)d_in[3];
    const float* W_img  = (const float*)d_in[4];
    const float* b_img  = (const float*)d_in[5];
    const float* W1 = (const float*)d_in[6];
    const float* b1 = (const float*)d_in[7];
    const float* W2 = (const float*)d_in[8];
    const float* b2 = (const float*)d_in[9];
    const float* W3 = (const float*)d_in[10];
    const float* b3 = (const float*)d_in[11];
    const float* W_fin = (const float*)d_in[12];
    const float* b_fin = (const float*)d_in[13];
    const int* src = (const int*)d_in[14];
    const int* dst = (const int*)d_in[15];

    const int N   = in_sizes[0];
    const int GLV = in_sizes[1] / N;   // 300
    const int FD  = in_sizes[5];       // 254
    const int IF  = in_sizes[7];       // 508
    const int E   = in_sizes[14];

    const int GLVp = 320;
    const int FDp  = 256;
    const int IFp  = 512;
    const int EP   = E + 8 * N;        // padded edge capacity

    char* base = (char*)d_ws;
    size_t off = 0;
    auto alloc = [&](size_t bytes) -> void* {
        void* p = base + off;
        off = (off + bytes + 255) & ~(size_t)255;
        return p;
    };

    // zeroed region: ns, nd (degrees), fill, z  (contiguous)
    float* ns  = (float*)alloc((size_t)N * 4);
    float* nd  = (float*)alloc((size_t)N * 4);
    int* fill  = (int*)alloc((size_t)N * 4);
    float* z   = (float*)alloc((size_t)N * 4);
    size_t zero_bytes = (size_t)((char*)(z + N) - (char*)ns);
    float* tv  = (float*)alloc((size_t)N * 4);
    float* ce  = (float*)alloc((size_t)FD * 4);
    float* u   = (float*)alloc((size_t)IF * 4);
    float* ov  = (float*)alloc((size_t)N * 4);
    int* rp    = (int*)alloc((size_t)(N + 1) * 4);
    int* bsum  = (int*)alloc(64 * 4);
    int2* payload = (int2*)alloc((size_t)EP * 8);
    unsigned short* WwP  = (unsigned short*)alloc((size_t)FDp * GLVp * 2);
    unsigned short* W1hT = (unsigned short*)alloc((size_t)IFp * FDp * 2);
    unsigned short* W2T  = (unsigned short*)alloc((size_t)IFp * IFp * 2);
    unsigned short* glove_bf = (unsigned short*)alloc((size_t)N * GLVp * 2);
    unsigned short* we       = (unsigned short*)alloc((size_t)N * FDp * 2);
    unsigned short* h12      = (unsigned short*)alloc((size_t)N * IFp * 2);
    unsigned short* aggwe = glove_bf;
    unsigned short* agg2  = glove_bf;
    unsigned short* h1 = h12;

    hipMemsetAsync(ns, 0, zero_bytes, stream);
    hipMemsetAsync(payload, 0, (size_t)EP * 8, stream);  // padding edges: {s=0, w=0}

    int gE = (E + TPB - 1) / TPB;
    int gN = (N + TPB - 1) / TPB;
    int nb = (N + 1023) / 1024;

    // CSR build + norms
    deg_kernel<<<gE, TPB, 0, stream>>>(src, dst, ns, nd, E);
    scan1<<<nb, 1024, 0, stream>>>(nd, rp, bsum, N);
    scan2<<<1, 64, 0, stream>>>(bsum, nb);
    scan3<<<nb, 1024, 0, stream>>>(rp, bsum, N);
    norm_kernel<<<gN, TPB, 0, stream>>>(ns, nd, N);
    scatter_kernel<<<gE, TPB, 0, stream>>>(src, dst, rp, fill, ns, payload, E);
    st_kernel<<<(N + 3) / 4, 256, 0, stream>>>(rp, payload, nd, tv, N);

    // ce = class_embed @ W_img.T + b_img ; u = ce @ W1[:FD, :]
    gemv_rows<<<FD, TPB, 0, stream>>>(class_embed, W_img, b_img, ce, N);
    u_kernel<<<IF, 64, 0, stream>>>(ce, W1, u, FD, IF);

    // conversions
    {
        int cpr = GLVp / 4;
        int tot = N * cpr;
        pad_convert4<<<(tot + 255) / 256, 256, 0, stream>>>(all_glove, GLV, N, glove_bf, GLVp, N, cpr);
        int tot2 = FDp * cpr;
        pad_convert4<<<(tot2 + 255) / 256, 256, 0, stream>>>(W_word, GLV, FD, WwP, GLVp, FDp, cpr);
    }
    {
        dim3 g(FDp / 32, IFp / 32);
        transpose_pad<<<g, dim3(32, 8), 0, stream>>>(W1 + (size_t)FD * IF, FD, IF, IF, W1hT, IFp, FDp);
    }
    {
        dim3 g(IFp / 32, IFp / 32);
        transpose_pad<<<g, dim3(32, 8), 0, stream>>>(W2, IF, IF, IF, W2T, IFp, IFp);
    }

    int mtiles = (N + 127) / 128;

    // we = all_glove @ W_word.T + b_word   [N][256] bf16
    {
        dim3 g(FDp / 128, mtiles);
        mfma_gemm<<<g, 256, 0, stream>>>(glove_bf, WwP, b_word, nullptr, nullptr, nullptr,
                                         nullptr, nullptr, we, N, FD, GLVp, FDp, 0);
    }
    // SpMM1: aggwe = sum w*we[s]   [N][256]
    spmm_bf16_cols<<<(N + 3) / 4, 256, 0, stream>>>(rp, payload, we, aggwe, N, FDp, 0);
    // h1 = relu(nd[r]*(aggwe @ W1[FD:,:]) + tv[r]*u[c] + b1)   [N][512]
    {
        dim3 g(IFp / 128, mtiles);
        mfma_gemm<<<g, 256, 0, stream>>>(aggwe, W1hT, b1, nd, tv, u,
                                         nullptr, nullptr, h1, N, IF, FDp, IFp, 1);
    }
    // SpMM2: agg2 = sum w*h1[s]   [N][512]  (two column passes, halved working set)
    spmm_bf16_cols<<<(N + 3) / 4, 256, 0, stream>>>(rp, payload, h1, agg2, N, IFp, 0);
    spmm_bf16_cols<<<(N + 3) / 4, 256, 0, stream>>>(rp, payload, h1, agg2, N, IFp, 256);
    // gemm2 fused: z[r] = relu(nd[r]*(agg2 @ W2) + b2) @ W3   (no C write)
    {
        dim3 g(IFp / 128, mtiles);
        mfma_gemm<<<g, 256, 0, stream>>>(agg2, W2T, b2, nd, nullptr, nullptr,
                                         W3, z, nullptr, N, IF, IFp, IFp, 1);
    }
    // o = relu(nd * gather(w*z) + b3)
    z_gather<<<(N + 3) / 4, 256, 0, stream>>>(rp, payload, z, nd, b3, ov, N);
    // out = o @ W_fin.T + b_fin
    gemv_rows<<<FD, TPB, 0, stream>>>(ov, W_fin, b_fin, (float*)d_out, N);
}

// Round 7
// 381.274 us; speedup vs baseline: 7.1132x; 1.1224x over previous
//
#include <hip/hip_runtime.h>
#include <hip/hip_bf16.h>

#define TPB 256
#define NB_E 32          // edge chunks for counting sort
#define HTPB 512         // threads per hist/scatter block
#define NHALF_LDS 10240  // LDS histogram capacity (ints) per half-range

typedef __attribute__((ext_vector_type(8))) short bf16x8_t;
typedef __attribute__((ext_vector_type(4))) float f32x4_t;
typedef __attribute__((ext_vector_type(8))) unsigned short u16x8_t;
typedef __attribute__((ext_vector_type(4))) unsigned short u16x4_t;

__device__ __forceinline__ float bf2f(unsigned short u) {
    return __uint_as_float(((unsigned)u) << 16);
}
__device__ __forceinline__ unsigned short f2bf(float f) {
    unsigned x = __float_as_uint(f);
    unsigned r = (x + 0x7fff + ((x >> 16) & 1)) >> 16;  // RNE
    return (unsigned short)r;
}

// ---------------- CSR build via counting sort (no global atomics) ----------------

// per-(chunk, variant) LDS histogram. variant: 0=dst lo-half, 1=dst hi-half, 2=src lo, 3=src hi
__global__ __launch_bounds__(HTPB) void hist_kernel(
    const int* __restrict__ src, const int* __restrict__ dst,
    int* __restrict__ histD, int* __restrict__ histS,
    int E, int N, int nhalf, int chunk) {
    __shared__ int h[NHALF_LDS];
    int b = blockIdx.x, var = blockIdx.y;
    const int* arr = (var < 2) ? dst : src;
    int lo = (var & 1) * nhalf;
    int hi = min(lo + nhalf, N);
    int cnt = hi - lo;
    for (int i = threadIdx.x; i < cnt; i += HTPB) h[i] = 0;
    __syncthreads();
    int beg = b * chunk, end = min(E, beg + chunk);
    for (int i = beg + threadIdx.x; i < end; i += HTPB) {
        int v = arr[i];
        if (v >= lo && v < hi) atomicAdd(&h[v - lo], 1);
    }
    __syncthreads();
    int* out = ((var < 2) ? histD : histS) + (size_t)b * N + lo;
    for (int i = threadIdx.x; i < cnt; i += HTPB) out[i] = h[i];
}

// per-node: sum partials -> degrees -> norms + padded deg_in
__global__ void degreduce_kernel(const int* __restrict__ histD, const int* __restrict__ histS,
                                 float* __restrict__ ns, float* __restrict__ nd,
                                 int* __restrict__ degp, int N) {
    int n = blockIdx.x * blockDim.x + threadIdx.x;
    if (n >= N) return;
    int di = 0, dout = 0;
    for (int b = 0; b < NB_E; b++) {
        di += histD[(size_t)b * N + n];
        dout += histS[(size_t)b * N + n];
    }
    nd[n] = di > 0 ? rsqrtf((float)di) : 0.f;
    ns[n] = dout > 0 ? rsqrtf((float)dout) : 0.f;
    degp[n] = (di + 7) & ~7;  // pad each list to multiple of 8
}

// phase 1: block-local inclusive scan of padded degrees -> rp[i+1]; block sum -> bsum[b]
__global__ __launch_bounds__(1024) void scan1(const int* __restrict__ degp,
                                              int* __restrict__ rp, int* __restrict__ bsum, int n) {
    __shared__ int buf[1024];
    int b = blockIdx.x;
    int i = b * 1024 + threadIdx.x;
    int v = (i < n) ? degp[i] : 0;
    buf[threadIdx.x] = v;
    __syncthreads();
    for (int off = 1; off < 1024; off <<= 1) {
        int t = (threadIdx.x >= off) ? buf[threadIdx.x - off] : 0;
        __syncthreads();
        buf[threadIdx.x] += t;
        __syncthreads();
    }
    if (i < n) rp[i + 1] = buf[threadIdx.x];
    if (threadIdx.x == 1023) bsum[b] = buf[1023];
    if (b == 0 && threadIdx.x == 0) rp[0] = 0;
}

__global__ void scan2(int* __restrict__ bsum, int nb) {
    int lane = threadIdx.x;
    int v = (lane < nb) ? bsum[lane] : 0;
    for (int off = 1; off < 64; off <<= 1) {
        int t = __shfl_up(v, off);
        if (lane >= off) v += t;
    }
    if (lane < nb) bsum[lane] = v;
}

__global__ __launch_bounds__(1024) void scan3(int* __restrict__ rp, const int* __restrict__ bsum, int n) {
    int b = blockIdx.x;
    if (b == 0) return;
    int i = b * 1024 + threadIdx.x;
    if (i < n) rp[i + 1] += bsum[b - 1];
}

// gbase[b][n] = rp[n] + sum_{b'<b} histD[b'][n]
__global__ void gbase_kernel(const int* __restrict__ histD, const int* __restrict__ rp,
                             int* __restrict__ gbase, int N) {
    int n = blockIdx.x * blockDim.x + threadIdx.x;
    if (n >= N) return;
    int run = rp[n];
    for (int b = 0; b < NB_E; b++) {
        gbase[(size_t)b * N + n] = run;
        run += histD[(size_t)b * N + n];
    }
}

// scatter with LDS ranks; payload = {src, ns[src]}
__global__ __launch_bounds__(HTPB) void scatter2_kernel(
    const int* __restrict__ src, const int* __restrict__ dst,
    const int* __restrict__ gbase, const float* __restrict__ ns,
    int2* __restrict__ payload, int E, int N, int nhalf, int chunk) {
    __shared__ int h[NHALF_LDS];
    int b = blockIdx.x, half = blockIdx.y;
    int lo = half * nhalf;
    int hi = min(lo + nhalf, N);
    int cnt = hi - lo;
    for (int i = threadIdx.x; i < cnt; i += HTPB) h[i] = 0;
    __syncthreads();
    int beg = b * chunk, end = min(E, beg + chunk);
    for (int i = beg + threadIdx.x; i < end; i += HTPB) {
        int d = dst[i];
        if (d >= lo && d < hi) {
            int s = src[i];
            int rank = atomicAdd(&h[d - lo], 1);
            int pos = gbase[(size_t)b * N + d] + rank;
            payload[pos] = make_int2(s, __float_as_int(ns[s]));
        }
    }
}

// t[d] = nd[d] * sum_e w_e   (padding has w=0)
__global__ __launch_bounds__(256) void st_kernel(const int* __restrict__ rp,
                                                 const int2* __restrict__ payload,
                                                 const float* __restrict__ nd,
                                                 float* __restrict__ tv, int n) {
    int d = blockIdx.x * 4 + (threadIdx.x >> 6);
    if (d >= n) return;
    int lane = threadIdx.x & 63;
    int beg = rp[d], end = rp[d + 1];
    float acc = 0.f;
    for (int e = beg + lane; e < end; e += 64) acc += __int_as_float(payload[e].y);
    for (int off = 32; off > 0; off >>= 1) acc += __shfl_down(acc, off);
    if (lane == 0) tv[d] = acc * nd[d];
}

// ---------------- small GEMV (fp32) ----------------

__global__ void gemv_rows(const float* __restrict__ vec, const float* __restrict__ Mat,
                          const float* __restrict__ bias, float* __restrict__ out, int n) {
    int j = blockIdx.x;
    const float* row = Mat + (size_t)j * n;
    float s = 0.f;
    for (int i = threadIdx.x; i < n; i += blockDim.x) s += vec[i] * row[i];
    __shared__ float red[TPB];
    red[threadIdx.x] = s;
    __syncthreads();
    for (int o = TPB / 2; o > 0; o >>= 1) {
        if (threadIdx.x < o) red[threadIdx.x] += red[threadIdx.x + o];
        __syncthreads();
    }
    if (threadIdx.x == 0) out[j] = red[0] + (bias ? bias[j] : 0.f);
}

__global__ __launch_bounds__(64) void u_kernel(const float* __restrict__ ce, const float* __restrict__ W1,
                                               float* __restrict__ u, int FD, int IF) {
    int j = blockIdx.x;
    int lane = threadIdx.x;
    float s = 0.f;
    for (int i = lane; i < FD; i += 64) s += ce[i] * W1[(size_t)i * IF + j];
    for (int off = 32; off > 0; off >>= 1) s += __shfl_down(s, off);
    if (lane == 0) u[j] = s;
}

// ---------------- conversion kernels ----------------

__global__ void pad_convert4(const float* __restrict__ in, int icols, int irows,
                             unsigned short* __restrict__ out, int ocols, int orows, int cpr) {
    int idx = blockIdx.x * blockDim.x + threadIdx.x;
    int row = idx / cpr;
    int c4 = (idx - row * cpr) * 4;
    if (row >= orows) return;
    float4 v = make_float4(0.f, 0.f, 0.f, 0.f);
    if (row < irows && c4 < icols)
        v = *(const float4*)(in + (size_t)row * icols + c4);
    u16x4_t o;
    o[0] = f2bf(v.x); o[1] = f2bf(v.y); o[2] = f2bf(v.z); o[3] = f2bf(v.w);
    *(u16x4_t*)(out + (size_t)row * ocols + c4) = o;
}

__global__ void transpose_pad(const float* __restrict__ W, int rows, int cols, int ldw,
                              unsigned short* __restrict__ out, int orows, int ocols) {
    __shared__ float tile[32][33];
    int k0 = blockIdx.x * 32, n0 = blockIdx.y * 32;
    int tx = threadIdx.x, ty = threadIdx.y;  // 32 x 8
    for (int i = 0; i < 32; i += 8) {
        int k = k0 + ty + i, n = n0 + tx;
        tile[ty + i][tx] = (k < rows && n < cols) ? W[(size_t)k * ldw + n] : 0.f;
    }
    __syncthreads();
    for (int i = 0; i < 32; i += 8) {
        int n = n0 + ty + i, k = k0 + tx;
        if (n < orows && k < ocols) out[(size_t)n * ocols + k] = f2bf(tile[tx][ty + i]);
    }
}

// ---------------- bf16 MFMA GEMM ----------------
// Optional fused z-epilogue: zout[row] += sum_col relu'd(v[row,col]) * w3[col] (fp32 atomics).
// If C == nullptr the bf16 tile is not written.
__global__ __launch_bounds__(256) void mfma_gemm(
    const unsigned short* __restrict__ A, const unsigned short* __restrict__ Bt,
    const float* __restrict__ bias, const float* __restrict__ rowscale,
    const float* __restrict__ tvec, const float* __restrict__ uvec,
    const float* __restrict__ w3, float* __restrict__ zout,
    unsigned short* __restrict__ C, int M, int Nn, int Kp, int Cld, int relu) {
    __shared__ unsigned short As[128 * 32];
    __shared__ unsigned short Bs[128 * 32];
    int tid = threadIdx.x;
    int lane = tid & 63;
    int wave = tid >> 6;
    int wm = wave >> 1, wn = wave & 1;  // 2x2 waves, each 64x64
    int lg = lane >> 4, lt = lane & 15;
    int row0 = blockIdx.y * 128, col0 = blockIdx.x * 128;

    f32x4_t acc[4][4] = {};

    int nk = Kp >> 5;
    for (int kp = 0; kp < nk; kp++) {
        int k0 = kp << 5;
#pragma unroll
        for (int i = 0; i < 2; i++) {
            int cid = tid + i * 256;
            int r = cid >> 2, c = cid & 3;
            int sw = c ^ ((r >> 1) & 3);
            int4 av = make_int4(0, 0, 0, 0);
            int grA = row0 + r;
            if (grA < M) av = *(const int4*)(A + (size_t)grA * Kp + k0 + (c << 3));
            *(int4*)(As + r * 32 + sw * 8) = av;
            int4 bv = *(const int4*)(Bt + (size_t)(col0 + r) * Kp + k0 + (c << 3));
            *(int4*)(Bs + r * 32 + sw * 8) = bv;
        }
        __syncthreads();
        bf16x8_t af[4], bfr[4];
#pragma unroll
        for (int mi = 0; mi < 4; mi++) {
            int r = wm * 64 + mi * 16 + lt;
            int sw = lg ^ ((r >> 1) & 3);
            af[mi] = *(const bf16x8_t*)(As + r * 32 + sw * 8);
        }
#pragma unroll
        for (int ni = 0; ni < 4; ni++) {
            int r = wn * 64 + ni * 16 + lt;
            int sw = lg ^ ((r >> 1) & 3);
            bfr[ni] = *(const bf16x8_t*)(Bs + r * 32 + sw * 8);
        }
#pragma unroll
        for (int mi = 0; mi < 4; mi++)
#pragma unroll
            for (int ni = 0; ni < 4; ni++)
                acc[mi][ni] = __builtin_amdgcn_mfma_f32_16x16x32_bf16(af[mi], bfr[ni], acc[mi][ni], 0, 0, 0);
        __syncthreads();
    }

#pragma unroll
    for (int mi = 0; mi < 4; mi++) {
#pragma unroll
        for (int r = 0; r < 4; r++) {
            int row = row0 + wm * 64 + mi * 16 + lg * 4 + r;
            if (row >= M) continue;
            float rs = rowscale ? rowscale[row] : 1.f;
            float tvr = tvec ? tvec[row] : 0.f;
            float zp = 0.f;
#pragma unroll
            for (int ni = 0; ni < 4; ni++) {
                int colb = col0 + wn * 64 + ni * 16 + lt;
                float v = 0.f;
                if (colb < Nn) {
                    v = acc[mi][ni][r] * rs;
                    if (bias) v += bias[colb];
                    if (tvec) v += tvr * uvec[colb];
                    if (relu) v = fmaxf(v, 0.f);
                    if (w3) zp += v * w3[colb];
                }
                if (C) C[(size_t)row * Cld + colb] = f2bf(v);
            }
            if (w3) {
                zp += __shfl_xor(zp, 1);
                zp += __shfl_xor(zp, 2);
                zp += __shfl_xor(zp, 4);
                zp += __shfl_xor(zp, 8);
                if (lt == 0) atomicAdd(&zout[row], zp);
            }
        }
    }
}

// ---------------- SpMM (CSR gather, payload, 8-edge unroll, tail-free) ----------------
// Columns [c0, c0+256) of X (row stride ld); one wave per node, u16x4/lane.
__global__ __launch_bounds__(256) void spmm_bf16_cols(
    const int* __restrict__ rp, const int2* __restrict__ payload,
    const unsigned short* __restrict__ X, unsigned short* __restrict__ Y,
    int n, int ld, int c0) {
    int node = blockIdx.x * 4 + (threadIdx.x >> 6);
    if (node >= n) return;
    int lane = threadIdx.x & 63;
    const unsigned short* Xo = X + c0 + lane * 4;
    int beg = rp[node], end = rp[node + 1];
    float acc[4] = {};
    for (int e = beg; e < end; e += 8) {
        int2 p[8];
#pragma unroll
        for (int j = 0; j < 8; j++) p[j] = payload[e + j];
        u16x4_t v[8];
#pragma unroll
        for (int j = 0; j < 8; j++) v[j] = *(const u16x4_t*)(Xo + (size_t)p[j].x * ld);
#pragma unroll
        for (int j = 0; j < 8; j++) {
            float w = __int_as_float(p[j].y);
#pragma unroll
            for (int c = 0; c < 4; c++) acc[c] += w * bf2f(v[j][c]);
        }
    }
    u16x4_t o;
#pragma unroll
    for (int c = 0; c < 4; c++) o[c] = f2bf(acc[c]);
    *(u16x4_t*)(Y + (size_t)node * ld + c0 + lane * 4) = o;
}

// ---------------- z path ----------------

__global__ __launch_bounds__(256) void z_gather(const int* __restrict__ rp,
                                                const int2* __restrict__ payload,
                                                const float* __restrict__ z,
                                                const float* __restrict__ nd, const float* __restrict__ b3,
                                                float* __restrict__ o, int n) {
    int d = blockIdx.x * 4 + (threadIdx.x >> 6);
    if (d >= n) return;
    int lane = threadIdx.x & 63;
    int beg = rp[d], end = rp[d + 1];
    float acc = 0.f;
    for (int e = beg + lane; e < end; e += 64) {
        int2 p = payload[e];
        acc += __int_as_float(p.y) * z[p.x];
    }
    for (int off = 32; off > 0; off >>= 1) acc += __shfl_down(acc, off);
    if (lane == 0) o[d] = fmaxf(nd[d] * acc + b3[0], 0.f);
}

// ---------------- launch ----------------

extern "C" void kernel_launch(void* const* d_in, const int* in_sizes, int n_in,
                              void* d_out, int out_size, void* d_ws, size_t ws_size,
                              hipStream_t stream) {
    const float* class_embed = (const float*)d_in[0];
    const float* all_glove   = (const float*)d_in[1];
    const float* W_word = (const float*)d_in[2];
    const float* b_word = (const float*)d_in[3];
    const float* W_img  = (const float*)d_in[4];
    const float* b_img  = (const float*)d_in[5];
    const float* W1 = (const float*)d_in[6];
    const float* b1 = (const float*)d_in[7];
    const float* W2 = (const float*)d_in[8];
    const float* b2 = (const float*)d_in[9];
    const float* W3 = (const float*)d_in[10];
    const float* b3 = (const float*)d_in[11];
    const float* W_fin = (const float*)d_in[12];
    const float* b_fin = (const float*)d_in[13];
    const int* src = (const int*)d_in[14];
    const int* dst = (const int*)d_in[15];

    const int N   = in_sizes[0];
    const int GLV = in_sizes[1] / N;   // 300
    const int FD  = in_sizes[5];       // 254
    const int IF  = in_sizes[7];       // 508
    const int E   = in_sizes[14];

    const int GLVp = 320;
    const int FDp  = 256;
    const int IFp  = 512;
    const int EP   = E + 8 * N;            // padded edge capacity
    const int nhalf = (N + 1) / 2;         // <= NHALF_LDS
    const int chunk = (E + NB_E - 1) / NB_E;

    char* base = (char*)d_ws;
    size_t off = 0;
    auto alloc = [&](size_t bytes) -> void* {
        void* p = base + off;
        off = (off + bytes + 255) & ~(size_t)255;
        return p;
    };

    float* ns  = (float*)alloc((size_t)N * 4);
    float* nd  = (float*)alloc((size_t)N * 4);
    float* z   = (float*)alloc((size_t)N * 4);   // zeroed (atomic accum)
    float* tv  = (float*)alloc((size_t)N * 4);
    float* ce  = (float*)alloc((size_t)FD * 4);
    float* u   = (float*)alloc((size_t)IF * 4);
    float* ov  = (float*)alloc((size_t)N * 4);
    int* degp  = (int*)alloc((size_t)N * 4);
    int* rp    = (int*)alloc((size_t)(N + 1) * 4);
    int* bsum  = (int*)alloc(64 * 4);
    int* histD = (int*)alloc((size_t)NB_E * N * 4);
    int* histS = (int*)alloc((size_t)NB_E * N * 4);
    int* gbase = (int*)alloc((size_t)NB_E * N * 4);
    int2* payload = (int2*)alloc((size_t)EP * 8);
    unsigned short* WwP  = (unsigned short*)alloc((size_t)FDp * GLVp * 2);
    unsigned short* W1hT = (unsigned short*)alloc((size_t)IFp * FDp * 2);
    unsigned short* W2T  = (unsigned short*)alloc((size_t)IFp * IFp * 2);
    unsigned short* glove_bf = (unsigned short*)alloc((size_t)N * GLVp * 2);
    unsigned short* we       = (unsigned short*)alloc((size_t)N * FDp * 2);
    unsigned short* h12      = (unsigned short*)alloc((size_t)N * IFp * 2);
    unsigned short* aggwe = glove_bf;
    unsigned short* agg2  = glove_bf;
    unsigned short* h1 = h12;

    hipMemsetAsync(z, 0, (size_t)N * 4, stream);
    hipMemsetAsync(payload, 0, (size_t)EP * 8, stream);  // padding edges: {s=0, w=0}

    int gN = (N + TPB - 1) / TPB;
    int nb = (N + 1023) / 1024;

    // CSR build: hist -> degrees/norms -> scan -> gbase -> rank-scatter
    {
        dim3 g(NB_E, 4);
        hist_kernel<<<g, HTPB, 0, stream>>>(src, dst, histD, histS, E, N, nhalf, chunk);
    }
    degreduce_kernel<<<gN, TPB, 0, stream>>>(histD, histS, ns, nd, degp, N);
    scan1<<<nb, 1024, 0, stream>>>(degp, rp, bsum, N);
    scan2<<<1, 64, 0, stream>>>(bsum, nb);
    scan3<<<nb, 1024, 0, stream>>>(rp, bsum, N);
    gbase_kernel<<<gN, TPB, 0, stream>>>(histD, rp, gbase, N);
    {
        dim3 g(NB_E, 2);
        scatter2_kernel<<<g, HTPB, 0, stream>>>(src, dst, gbase, ns, payload, E, N, nhalf, chunk);
    }
    st_kernel<<<(N + 3) / 4, 256, 0, stream>>>(rp, payload, nd, tv, N);

    // ce = class_embed @ W_img.T + b_img ; u = ce @ W1[:FD, :]
    gemv_rows<<<FD, TPB, 0, stream>>>(class_embed, W_img, b_img, ce, N);
    u_kernel<<<IF, 64, 0, stream>>>(ce, W1, u, FD, IF);

    // conversions
    {
        int cpr = GLVp / 4;
        int tot = N * cpr;
        pad_convert4<<<(tot + 255) / 256, 256, 0, stream>>>(all_glove, GLV, N, glove_bf, GLVp, N, cpr);
        int tot2 = FDp * cpr;
        pad_convert4<<<(tot2 + 255) / 256, 256, 0, stream>>>(W_word, GLV, FD, WwP, GLVp, FDp, cpr);
    }
    {
        dim3 g(FDp / 32, IFp / 32);
        transpose_pad<<<g, dim3(32, 8), 0, stream>>>(W1 + (size_t)FD * IF, FD, IF, IF, W1hT, IFp, FDp);
    }
    {
        dim3 g(IFp / 32, IFp / 32);
        transpose_pad<<<g, dim3(32, 8), 0, stream>>>(W2, IF, IF, IF, W2T, IFp, IFp);
    }

    int mtiles = (N + 127) / 128;

    // we = all_glove @ W_word.T + b_word   [N][256] bf16
    {
        dim3 g(FDp / 128, mtiles);
        mfma_gemm<<<g, 256, 0, stream>>>(glove_bf, WwP, b_word, nullptr, nullptr, nullptr,
                                         nullptr, nullptr, we, N, FD, GLVp, FDp, 0);
    }
    // SpMM1: aggwe = sum w*we[s]   [N][256]
    spmm_bf16_cols<<<(N + 3) / 4, 256, 0, stream>>>(rp, payload, we, aggwe, N, FDp, 0);
    // h1 = relu(nd[r]*(aggwe @ W1[FD:,:]) + tv[r]*u[c] + b1)   [N][512]
    {
        dim3 g(IFp / 128, mtiles);
        mfma_gemm<<<g, 256, 0, stream>>>(aggwe, W1hT, b1, nd, tv, u,
                                         nullptr, nullptr, h1, N, IF, FDp, IFp, 1);
    }
    // SpMM2: agg2 = sum w*h1[s]   [N][512]  (two column passes)
    spmm_bf16_cols<<<(N + 3) / 4, 256, 0, stream>>>(rp, payload, h1, agg2, N, IFp, 0);
    spmm_bf16_cols<<<(N + 3) / 4, 256, 0, stream>>>(rp, payload, h1, agg2, N, IFp, 256);
    // gemm2 fused: z[r] = relu(nd[r]*(agg2 @ W2) + b2) @ W3   (no C write)
    {
        dim3 g(IFp / 128, mtiles);
        mfma_gemm<<<g, 256, 0, stream>>>(agg2, W2T, b2, nd, nullptr, nullptr,
                                         W3, z, nullptr, N, IF, IFp, IFp, 1);
    }
    // o = relu(nd * gather(w*z) + b3)
    z_gather<<<(N + 3) / 4, 256, 0, stream>>>(rp, payload, z, nd, b3, ov, N);
    // out = o @ W_fin.T + b_fin
    gemv_rows<<<FD, TPB, 0, stream>>>(ov, W_fin, b_fin, (float*)d_out, N);
}

// Round 8
// 376.653 us; speedup vs baseline: 7.2005x; 1.0123x over previous
//
#include <hip/hip_runtime.h>
#include <hip/hip_bf16.h>

#define TPB 256
#define NB_E 32          // edge chunks for counting sort
#define HTPB 512         // threads per hist/scatter block
#define NHALF_LDS 10240  // LDS histogram capacity (ints) per half-range

typedef __attribute__((ext_vector_type(8))) short bf16x8_t;
typedef __attribute__((ext_vector_type(4))) float f32x4_t;
typedef __attribute__((ext_vector_type(8))) unsigned short u16x8_t;
typedef __attribute__((ext_vector_type(4))) unsigned short u16x4_t;

__device__ __forceinline__ float bf2f(unsigned short u) {
    return __uint_as_float(((unsigned)u) << 16);
}
__device__ __forceinline__ unsigned short f2bf(float f) {
    unsigned x = __float_as_uint(f);
    unsigned r = (x + 0x7fff + ((x >> 16) & 1)) >> 16;  // RNE
    return (unsigned short)r;
}

// async global -> LDS, 16 bytes per lane (dest must be wave-uniform base + lane*16)
__device__ __forceinline__ void gload16(const unsigned short* g, unsigned short* l) {
    __builtin_amdgcn_global_load_lds(
        (const __attribute__((address_space(1))) unsigned int*)(const void*)g,
        (__attribute__((address_space(3))) unsigned int*)(void*)l, 16, 0, 0);
}

// ---------------- CSR build via counting sort (no global atomics) ----------------

// per-(chunk, variant) LDS histogram. variant: 0=dst lo-half, 1=dst hi-half, 2=src lo, 3=src hi
__global__ __launch_bounds__(HTPB) void hist_kernel(
    const int* __restrict__ src, const int* __restrict__ dst,
    int* __restrict__ histD, int* __restrict__ histS,
    int E, int N, int nhalf, int chunk) {
    __shared__ int h[NHALF_LDS];
    int b = blockIdx.x, var = blockIdx.y;
    const int* arr = (var < 2) ? dst : src;
    int lo = (var & 1) * nhalf;
    int hi = min(lo + nhalf, N);
    int cnt = hi - lo;
    for (int i = threadIdx.x; i < cnt; i += HTPB) h[i] = 0;
    __syncthreads();
    int beg = b * chunk, end = min(E, beg + chunk);
    for (int i = beg + threadIdx.x; i < end; i += HTPB) {
        int v = arr[i];
        if (v >= lo && v < hi) atomicAdd(&h[v - lo], 1);
    }
    __syncthreads();
    int* out = ((var < 2) ? histD : histS) + (size_t)b * N + lo;
    for (int i = threadIdx.x; i < cnt; i += HTPB) out[i] = h[i];
}

// per-node: sum partials -> degrees -> norms + padded deg_in
__global__ void degreduce_kernel(const int* __restrict__ histD, const int* __restrict__ histS,
                                 float* __restrict__ ns, float* __restrict__ nd,
                                 int* __restrict__ degp, int N) {
    int n = blockIdx.x * blockDim.x + threadIdx.x;
    if (n >= N) return;
    int di = 0, dout = 0;
    for (int b = 0; b < NB_E; b++) {
        di += histD[(size_t)b * N + n];
        dout += histS[(size_t)b * N + n];
    }
    nd[n] = di > 0 ? rsqrtf((float)di) : 0.f;
    ns[n] = dout > 0 ? rsqrtf((float)dout) : 0.f;
    degp[n] = (di + 7) & ~7;  // pad each list to multiple of 8
}

// phase 1: block-local inclusive scan of padded degrees -> rp[i+1]; block sum -> bsum[b]
__global__ __launch_bounds__(1024) void scan1(const int* __restrict__ degp,
                                              int* __restrict__ rp, int* __restrict__ bsum, int n) {
    __shared__ int buf[1024];
    int b = blockIdx.x;
    int i = b * 1024 + threadIdx.x;
    int v = (i < n) ? degp[i] : 0;
    buf[threadIdx.x] = v;
    __syncthreads();
    for (int off = 1; off < 1024; off <<= 1) {
        int t = (threadIdx.x >= off) ? buf[threadIdx.x - off] : 0;
        __syncthreads();
        buf[threadIdx.x] += t;
        __syncthreads();
    }
    if (i < n) rp[i + 1] = buf[threadIdx.x];
    if (threadIdx.x == 1023) bsum[b] = buf[1023];
    if (b == 0 && threadIdx.x == 0) rp[0] = 0;
}

__global__ void scan2(int* __restrict__ bsum, int nb) {
    int lane = threadIdx.x;
    int v = (lane < nb) ? bsum[lane] : 0;
    for (int off = 1; off < 64; off <<= 1) {
        int t = __shfl_up(v, off);
        if (lane >= off) v += t;
    }
    if (lane < nb) bsum[lane] = v;
}

__global__ __launch_bounds__(1024) void scan3(int* __restrict__ rp, const int* __restrict__ bsum, int n) {
    int b = blockIdx.x;
    if (b == 0) return;
    int i = b * 1024 + threadIdx.x;
    if (i < n) rp[i + 1] += bsum[b - 1];
}

// gbase[b][n] = rp[n] + sum_{b'<b} histD[b'][n]
__global__ void gbase_kernel(const int* __restrict__ histD, const int* __restrict__ rp,
                             int* __restrict__ gbase, int N) {
    int n = blockIdx.x * blockDim.x + threadIdx.x;
    if (n >= N) return;
    int run = rp[n];
    for (int b = 0; b < NB_E; b++) {
        gbase[(size_t)b * N + n] = run;
        run += histD[(size_t)b * N + n];
    }
}

// scatter with LDS ranks; payload = {src, ns[src]}
__global__ __launch_bounds__(HTPB) void scatter2_kernel(
    const int* __restrict__ src, const int* __restrict__ dst,
    const int* __restrict__ gbase, const float* __restrict__ ns,
    int2* __restrict__ payload, int E, int N, int nhalf, int chunk) {
    __shared__ int h[NHALF_LDS];
    int b = blockIdx.x, half = blockIdx.y;
    int lo = half * nhalf;
    int hi = min(lo + nhalf, N);
    int cnt = hi - lo;
    for (int i = threadIdx.x; i < cnt; i += HTPB) h[i] = 0;
    __syncthreads();
    int beg = b * chunk, end = min(E, beg + chunk);
    for (int i = beg + threadIdx.x; i < end; i += HTPB) {
        int d = dst[i];
        if (d >= lo && d < hi) {
            int s = src[i];
            int rank = atomicAdd(&h[d - lo], 1);
            int pos = gbase[(size_t)b * N + d] + rank;
            payload[pos] = make_int2(s, __float_as_int(ns[s]));
        }
    }
}

// t[d] = nd[d] * sum_e w_e   (padding has w=0)
__global__ __launch_bounds__(256) void st_kernel(const int* __restrict__ rp,
                                                 const int2* __restrict__ payload,
                                                 const float* __restrict__ nd,
                                                 float* __restrict__ tv, int n) {
    int d = blockIdx.x * 4 + (threadIdx.x >> 6);
    if (d >= n) return;
    int lane = threadIdx.x & 63;
    int beg = rp[d], end = rp[d + 1];
    float acc = 0.f;
    for (int e = beg + lane; e < end; e += 64) acc += __int_as_float(payload[e].y);
    for (int off = 32; off > 0; off >>= 1) acc += __shfl_down(acc, off);
    if (lane == 0) tv[d] = acc * nd[d];
}

// ---------------- small GEMV (fp32) ----------------

__global__ void gemv_rows(const float* __restrict__ vec, const float* __restrict__ Mat,
                          const float* __restrict__ bias, float* __restrict__ out, int n) {
    int j = blockIdx.x;
    const float* row = Mat + (size_t)j * n;
    float s = 0.f;
    for (int i = threadIdx.x; i < n; i += blockDim.x) s += vec[i] * row[i];
    __shared__ float red[TPB];
    red[threadIdx.x] = s;
    __syncthreads();
    for (int o = TPB / 2; o > 0; o >>= 1) {
        if (threadIdx.x < o) red[threadIdx.x] += red[threadIdx.x + o];
        __syncthreads();
    }
    if (threadIdx.x == 0) out[j] = red[0] + (bias ? bias[j] : 0.f);
}

__global__ __launch_bounds__(64) void u_kernel(const float* __restrict__ ce, const float* __restrict__ W1,
                                               float* __restrict__ u, int FD, int IF) {
    int j = blockIdx.x;
    int lane = threadIdx.x;
    float s = 0.f;
    for (int i = lane; i < FD; i += 64) s += ce[i] * W1[(size_t)i * IF + j];
    for (int off = 32; off > 0; off >>= 1) s += __shfl_down(s, off);
    if (lane == 0) u[j] = s;
}

// ---------------- conversion kernels ----------------

__global__ void pad_convert4(const float* __restrict__ in, int icols, int irows,
                             unsigned short* __restrict__ out, int ocols, int orows, int cpr) {
    int idx = blockIdx.x * blockDim.x + threadIdx.x;
    int row = idx / cpr;
    int c4 = (idx - row * cpr) * 4;
    if (row >= orows) return;
    float4 v = make_float4(0.f, 0.f, 0.f, 0.f);
    if (row < irows && c4 < icols)
        v = *(const float4*)(in + (size_t)row * icols + c4);
    u16x4_t o;
    o[0] = f2bf(v.x); o[1] = f2bf(v.y); o[2] = f2bf(v.z); o[3] = f2bf(v.w);
    *(u16x4_t*)(out + (size_t)row * ocols + c4) = o;
}

__global__ void transpose_pad(const float* __restrict__ W, int rows, int cols, int ldw,
                              unsigned short* __restrict__ out, int orows, int ocols) {
    __shared__ float tile[32][33];
    int k0 = blockIdx.x * 32, n0 = blockIdx.y * 32;
    int tx = threadIdx.x, ty = threadIdx.y;  // 32 x 8
    for (int i = 0; i < 32; i += 8) {
        int k = k0 + ty + i, n = n0 + tx;
        tile[ty + i][tx] = (k < rows && n < cols) ? W[(size_t)k * ldw + n] : 0.f;
    }
    __syncthreads();
    for (int i = 0; i < 32; i += 8) {
        int n = n0 + ty + i, k = k0 + tx;
        if (n < orows && k < ocols) out[(size_t)n * ocols + k] = f2bf(tile[tx][ty + i]);
    }
}

// ---------------- bf16 MFMA GEMM ----------------
// A must be padded to gridDim.y*128 rows (pad rows finite garbage, discarded in epilogue).
// XCD-aware bijective block swizzle: 4-consecutive logical blocks share an A-panel and
// land on the same XCD -> A fetched ~once from HBM.
// Staging via global_load_lds (16B/lane), swizzle applied on the GLOBAL source address.
__global__ __launch_bounds__(256) void mfma_gemm(
    const unsigned short* __restrict__ A, const unsigned short* __restrict__ Bt,
    const float* __restrict__ bias, const float* __restrict__ rowscale,
    const float* __restrict__ tvec, const float* __restrict__ uvec,
    const float* __restrict__ w3, float* __restrict__ zout,
    unsigned short* __restrict__ C, int M, int Nn, int Kp, int Cld, int relu) {
    __shared__ unsigned short As[128 * 32];
    __shared__ unsigned short Bs[128 * 32];
    int tid = threadIdx.x;
    int lane = tid & 63;
    int wave = tid >> 6;
    int wm = wave >> 1, wn = wave & 1;  // 2x2 waves, each 64x64
    int lg = lane >> 4, lt = lane & 15;

    // bijective XCD swizzle (m204): hw id -> contiguous logical chunk per XCD
    int nwg = gridDim.x * gridDim.y;
    int hid = blockIdx.y * gridDim.x + blockIdx.x;
    int q = nwg >> 3, r8 = nwg & 7;
    int xcd = hid & 7, pos = hid >> 3;
    int wg = (xcd < r8 ? xcd * (q + 1) : r8 * (q + 1) + (xcd - r8) * q) + pos;
    int row0 = (wg / gridDim.x) * 128, col0 = (wg % gridDim.x) * 128;

    f32x4_t acc[4][4] = {};

    int nk = Kp >> 5;
    for (int kp = 0; kp < nk; kp++) {
        int k0 = kp << 5;
#pragma unroll
        for (int i = 0; i < 2; i++) {
            int cid = tid + i * 256;
            int r = cid >> 2, c = cid & 3;
            int sw = c ^ ((r >> 1) & 3);  // pre-swizzle the SOURCE; LDS dest linear
            gload16(A + (size_t)(row0 + r) * Kp + k0 + (sw << 3), As + cid * 8);
            gload16(Bt + (size_t)(col0 + r) * Kp + k0 + (sw << 3), Bs + cid * 8);
        }
        __syncthreads();
        bf16x8_t af[4], bfr[4];
#pragma unroll
        for (int mi = 0; mi < 4; mi++) {
            int r = wm * 64 + mi * 16 + lt;
            int sw = lg ^ ((r >> 1) & 3);
            af[mi] = *(const bf16x8_t*)(As + r * 32 + sw * 8);
        }
#pragma unroll
        for (int ni = 0; ni < 4; ni++) {
            int r = wn * 64 + ni * 16 + lt;
            int sw = lg ^ ((r >> 1) & 3);
            bfr[ni] = *(const bf16x8_t*)(Bs + r * 32 + sw * 8);
        }
#pragma unroll
        for (int mi = 0; mi < 4; mi++)
#pragma unroll
            for (int ni = 0; ni < 4; ni++)
                acc[mi][ni] = __builtin_amdgcn_mfma_f32_16x16x32_bf16(af[mi], bfr[ni], acc[mi][ni], 0, 0, 0);
        __syncthreads();
    }

#pragma unroll
    for (int mi = 0; mi < 4; mi++) {
#pragma unroll
        for (int r = 0; r < 4; r++) {
            int row = row0 + wm * 64 + mi * 16 + lg * 4 + r;
            if (row >= M) continue;
            float rs = rowscale ? rowscale[row] : 1.f;
            float tvr = tvec ? tvec[row] : 0.f;
            float zp = 0.f;
#pragma unroll
            for (int ni = 0; ni < 4; ni++) {
                int colb = col0 + wn * 64 + ni * 16 + lt;
                float v = 0.f;
                if (colb < Nn) {
                    v = acc[mi][ni][r] * rs;
                    if (bias) v += bias[colb];
                    if (tvec) v += tvr * uvec[colb];
                    if (relu) v = fmaxf(v, 0.f);
                    if (w3) zp += v * w3[colb];
                }
                if (C) C[(size_t)row * Cld + colb] = f2bf(v);
            }
            if (w3) {
                zp += __shfl_xor(zp, 1);
                zp += __shfl_xor(zp, 2);
                zp += __shfl_xor(zp, 4);
                zp += __shfl_xor(zp, 8);
                if (lt == 0) atomicAdd(&zout[row], zp);
            }
        }
    }
}

// ---------------- SpMM (CSR gather, payload, 8-edge unroll, tail-free) ----------------
// Columns [c0, c0+256) of X (row stride ld); one wave per node, u16x4/lane.
__global__ __launch_bounds__(256) void spmm_bf16_cols(
    const int* __restrict__ rp, const int2* __restrict__ payload,
    const unsigned short* __restrict__ X, unsigned short* __restrict__ Y,
    int n, int ld, int c0) {
    int node = blockIdx.x * 4 + (threadIdx.x >> 6);
    if (node >= n) return;
    int lane = threadIdx.x & 63;
    const unsigned short* Xo = X + c0 + lane * 4;
    int beg = rp[node], end = rp[node + 1];
    float acc[4] = {};
    for (int e = beg; e < end; e += 8) {
        int2 p[8];
#pragma unroll
        for (int j = 0; j < 8; j++) p[j] = payload[e + j];
        u16x4_t v[8];
#pragma unroll
        for (int j = 0; j < 8; j++) v[j] = *(const u16x4_t*)(Xo + (size_t)p[j].x * ld);
#pragma unroll
        for (int j = 0; j < 8; j++) {
            float w = __int_as_float(p[j].y);
#pragma unroll
            for (int c = 0; c < 4; c++) acc[c] += w * bf2f(v[j][c]);
        }
    }
    u16x4_t o;
#pragma unroll
    for (int c = 0; c < 4; c++) o[c] = f2bf(acc[c]);
    *(u16x4_t*)(Y + (size_t)node * ld + c0 + lane * 4) = o;
}

// ---------------- z path ----------------

__global__ __launch_bounds__(256) void z_gather(const int* __restrict__ rp,
                                                const int2* __restrict__ payload,
                                                const float* __restrict__ z,
                                                const float* __restrict__ nd, const float* __restrict__ b3,
                                                float* __restrict__ o, int n) {
    int d = blockIdx.x * 4 + (threadIdx.x >> 6);
    if (d >= n) return;
    int lane = threadIdx.x & 63;
    int beg = rp[d], end = rp[d + 1];
    float acc = 0.f;
    for (int e = beg + lane; e < end; e += 64) {
        int2 p = payload[e];
        acc += __int_as_float(p.y) * z[p.x];
    }
    for (int off = 32; off > 0; off >>= 1) acc += __shfl_down(acc, off);
    if (lane == 0) o[d] = fmaxf(nd[d] * acc + b3[0], 0.f);
}

// ---------------- launch ----------------

extern "C" void kernel_launch(void* const* d_in, const int* in_sizes, int n_in,
                              void* d_out, int out_size, void* d_ws, size_t ws_size,
                              hipStream_t stream) {
    const float* class_embed = (const float*)d_in[0];
    const float* all_glove   = (const float*)d_in[1];
    const float* W_word = (const float*)d_in[2];
    const float* b_word = (const float*)d_in[3];
    const float* W_img  = (const float*)d_in[4];
    const float* b_img  = (const float*)d_in[5];
    const float* W1 = (const float*)d_in[6];
    const float* b1 = (const float*)d_in[7];
    const float* W2 = (const float*)d_in[8];
    const float* b2 = (const float*)d_in[9];
    const float* W3 = (const float*)d_in[10];
    const float* b3 = (const float*)d_in[11];
    const float* W_fin = (const float*)d_in[12];
    const float* b_fin = (const float*)d_in[13];
    const int* src = (const int*)d_in[14];
    const int* dst = (const int*)d_in[15];

    const int N   = in_sizes[0];
    const int GLV = in_sizes[1] / N;   // 300
    const int FD  = in_sizes[5];       // 254
    const int IF  = in_sizes[7];       // 508
    const int E   = in_sizes[14];

    const int GLVp = 320;
    const int FDp  = 256;
    const int IFp  = 512;
    const int Mp   = (N + 127) & ~127;     // padded row count for GEMM A operands
    const int EP   = E + 8 * N;            // padded edge capacity
    const int nhalf = (N + 1) / 2;         // <= NHALF_LDS
    const int chunk = (E + NB_E - 1) / NB_E;

    char* base = (char*)d_ws;
    size_t off = 0;
    auto alloc = [&](size_t bytes) -> void* {
        void* p = base + off;
        off = (off + bytes + 255) & ~(size_t)255;
        return p;
    };

    float* ns  = (float*)alloc((size_t)N * 4);
    float* nd  = (float*)alloc((size_t)N * 4);
    float* z   = (float*)alloc((size_t)N * 4);   // zeroed (atomic accum)
    float* tv  = (float*)alloc((size_t)N * 4);
    float* ce  = (float*)alloc((size_t)FD * 4);
    float* u   = (float*)alloc((size_t)IF * 4);
    float* ov  = (float*)alloc((size_t)N * 4);
    int* degp  = (int*)alloc((size_t)N * 4);
    int* rp    = (int*)alloc((size_t)(N + 1) * 4);
    int* bsum  = (int*)alloc(64 * 4);
    int* histD = (int*)alloc((size_t)NB_E * N * 4);
    int* histS = (int*)alloc((size_t)NB_E * N * 4);
    int* gbase = (int*)alloc((size_t)NB_E * N * 4);
    int2* payload = (int2*)alloc((size_t)EP * 8);
    unsigned short* WwP  = (unsigned short*)alloc((size_t)FDp * GLVp * 2);
    unsigned short* W1hT = (unsigned short*)alloc((size_t)IFp * FDp * 2);
    unsigned short* W2T  = (unsigned short*)alloc((size_t)IFp * IFp * 2);
    unsigned short* glove_bf = (unsigned short*)alloc((size_t)Mp * GLVp * 2);
    unsigned short* we       = (unsigned short*)alloc((size_t)Mp * FDp * 2);
    unsigned short* h12      = (unsigned short*)alloc((size_t)Mp * IFp * 2);
    unsigned short* aggwe = glove_bf;   // [Mp][256] after glove dead
    unsigned short* agg2  = glove_bf;   // [Mp][512] spans glove+we regions
    unsigned short* h1 = h12;

    hipMemsetAsync(z, 0, (size_t)N * 4, stream);
    hipMemsetAsync(payload, 0, (size_t)EP * 8, stream);  // padding edges: {s=0, w=0}

    int gN = (N + TPB - 1) / TPB;
    int nb = (N + 1023) / 1024;

    // CSR build: hist -> degrees/norms -> scan -> gbase -> rank-scatter
    {
        dim3 g(NB_E, 4);
        hist_kernel<<<g, HTPB, 0, stream>>>(src, dst, histD, histS, E, N, nhalf, chunk);
    }
    degreduce_kernel<<<gN, TPB, 0, stream>>>(histD, histS, ns, nd, degp, N);
    scan1<<<nb, 1024, 0, stream>>>(degp, rp, bsum, N);
    scan2<<<1, 64, 0, stream>>>(bsum, nb);
    scan3<<<nb, 1024, 0, stream>>>(rp, bsum, N);
    gbase_kernel<<<gN, TPB, 0, stream>>>(histD, rp, gbase, N);
    {
        dim3 g(NB_E, 2);
        scatter2_kernel<<<g, HTPB, 0, stream>>>(src, dst, gbase, ns, payload, E, N, nhalf, chunk);
    }
    st_kernel<<<(N + 3) / 4, 256, 0, stream>>>(rp, payload, nd, tv, N);

    // ce = class_embed @ W_img.T + b_img ; u = ce @ W1[:FD, :]
    gemv_rows<<<FD, TPB, 0, stream>>>(class_embed, W_img, b_img, ce, N);
    u_kernel<<<IF, 64, 0, stream>>>(ce, W1, u, FD, IF);

    // conversions (glove zero-padded to Mp rows so GEMM A-stage needs no M guard)
    {
        int cpr = GLVp / 4;
        int tot = Mp * cpr;
        pad_convert4<<<(tot + 255) / 256, 256, 0, stream>>>(all_glove, GLV, N, glove_bf, GLVp, Mp, cpr);
        int tot2 = FDp * cpr;
        pad_convert4<<<(tot2 + 255) / 256, 256, 0, stream>>>(W_word, GLV, FD, WwP, GLVp, FDp, cpr);
    }
    {
        dim3 g(FDp / 32, IFp / 32);
        transpose_pad<<<g, dim3(32, 8), 0, stream>>>(W1 + (size_t)FD * IF, FD, IF, IF, W1hT, IFp, FDp);
    }
    {
        dim3 g(IFp / 32, IFp / 32);
        transpose_pad<<<g, dim3(32, 8), 0, stream>>>(W2, IF, IF, IF, W2T, IFp, IFp);
    }

    int mtiles = Mp / 128;

    // we = all_glove @ W_word.T + b_word   [N][256] bf16
    {
        dim3 g(FDp / 128, mtiles);
        mfma_gemm<<<g, 256, 0, stream>>>(glove_bf, WwP, b_word, nullptr, nullptr, nullptr,
                                         nullptr, nullptr, we, N, FD, GLVp, FDp, 0);
    }
    // SpMM1: aggwe = sum w*we[s]   [N][256]
    spmm_bf16_cols<<<(N + 3) / 4, 256, 0, stream>>>(rp, payload, we, aggwe, N, FDp, 0);
    // h1 = relu(nd[r]*(aggwe @ W1[FD:,:]) + tv[r]*u[c] + b1)   [N][512]
    {
        dim3 g(IFp / 128, mtiles);
        mfma_gemm<<<g, 256, 0, stream>>>(aggwe, W1hT, b1, nd, tv, u,
                                         nullptr, nullptr, h1, N, IF, FDp, IFp, 1);
    }
    // SpMM2: agg2 = sum w*h1[s]   [N][512]  (two column passes)
    spmm_bf16_cols<<<(N + 3) / 4, 256, 0, stream>>>(rp, payload, h1, agg2, N, IFp, 0);
    spmm_bf16_cols<<<(N + 3) / 4, 256, 0, stream>>>(rp, payload, h1, agg2, N, IFp, 256);
    // gemm2 fused: z[r] = relu(nd[r]*(agg2 @ W2) + b2) @ W3   (no C write)
    {
        dim3 g(IFp / 128, mtiles);
        mfma_gemm<<<g, 256, 0, stream>>>(agg2, W2T, b2, nd, nullptr, nullptr,
                                         W3, z, nullptr, N, IF, IFp, IFp, 1);
    }
    // o = relu(nd * gather(w*z) + b3)
    z_gather<<<(N + 3) / 4, 256, 0, stream>>>(rp, payload, z, nd, b3, ov, N);
    // out = o @ W_fin.T + b_fin
    gemv_rows<<<FD, TPB, 0, stream>>>(ov, W_fin, b_fin, (float*)d_out, N);
}

// Round 9
// 369.932 us; speedup vs baseline: 7.3313x; 1.0182x over previous
//
#include <hip/hip_runtime.h>
#include <hip/hip_bf16.h>

#define TPB 256
#define NB_E 32          // edge chunks for counting sort
#define HTPB 512         // threads per hist/scatter block
#define NHALF_LDS 10240  // LDS histogram capacity (ints) per half-range

typedef __attribute__((ext_vector_type(8))) short bf16x8_t;
typedef __attribute__((ext_vector_type(4))) float f32x4_t;
typedef __attribute__((ext_vector_type(8))) unsigned short u16x8_t;
typedef __attribute__((ext_vector_type(4))) unsigned short u16x4_t;

__device__ __forceinline__ float bf2f(unsigned short u) {
    return __uint_as_float(((unsigned)u) << 16);
}
__device__ __forceinline__ unsigned short f2bf(float f) {
    unsigned x = __float_as_uint(f);
    unsigned r = (x + 0x7fff + ((x >> 16) & 1)) >> 16;  // RNE
    return (unsigned short)r;
}

// async global -> LDS, 16 bytes per lane (HW: readfirstlane(dest) + lane*16)
__device__ __forceinline__ void gload16(const unsigned short* g, unsigned short* l) {
    __builtin_amdgcn_global_load_lds(
        (const __attribute__((address_space(1))) unsigned int*)(const void*)g,
        (__attribute__((address_space(3))) unsigned int*)(void*)l, 16, 0, 0);
}

// ---------------- CSR build via counting sort (no global atomics) ----------------

__global__ __launch_bounds__(HTPB) void hist_kernel(
    const int* __restrict__ src, const int* __restrict__ dst,
    int* __restrict__ histD, int* __restrict__ histS,
    int E, int N, int nhalf, int chunk) {
    __shared__ int h[NHALF_LDS];
    int b = blockIdx.x, var = blockIdx.y;
    const int* arr = (var < 2) ? dst : src;
    int lo = (var & 1) * nhalf;
    int hi = min(lo + nhalf, N);
    int cnt = hi - lo;
    for (int i = threadIdx.x; i < cnt; i += HTPB) h[i] = 0;
    __syncthreads();
    int beg = b * chunk, end = min(E, beg + chunk);
    for (int i = beg + threadIdx.x; i < end; i += HTPB) {
        int v = arr[i];
        if (v >= lo && v < hi) atomicAdd(&h[v - lo], 1);
    }
    __syncthreads();
    int* out = ((var < 2) ? histD : histS) + (size_t)b * N + lo;
    for (int i = threadIdx.x; i < cnt; i += HTPB) out[i] = h[i];
}

__global__ void degreduce_kernel(const int* __restrict__ histD, const int* __restrict__ histS,
                                 float* __restrict__ ns, float* __restrict__ nd,
                                 int* __restrict__ degp, int N) {
    int n = blockIdx.x * blockDim.x + threadIdx.x;
    if (n >= N) return;
    int di = 0, dout = 0;
    for (int b = 0; b < NB_E; b++) {
        di += histD[(size_t)b * N + n];
        dout += histS[(size_t)b * N + n];
    }
    nd[n] = di > 0 ? rsqrtf((float)di) : 0.f;
    ns[n] = dout > 0 ? rsqrtf((float)dout) : 0.f;
    degp[n] = (di + 7) & ~7;  // pad each list to multiple of 8
}

__global__ __launch_bounds__(1024) void scan1(const int* __restrict__ degp,
                                              int* __restrict__ rp, int* __restrict__ bsum, int n) {
    __shared__ int buf[1024];
    int b = blockIdx.x;
    int i = b * 1024 + threadIdx.x;
    int v = (i < n) ? degp[i] : 0;
    buf[threadIdx.x] = v;
    __syncthreads();
    for (int off = 1; off < 1024; off <<= 1) {
        int t = (threadIdx.x >= off) ? buf[threadIdx.x - off] : 0;
        __syncthreads();
        buf[threadIdx.x] += t;
        __syncthreads();
    }
    if (i < n) rp[i + 1] = buf[threadIdx.x];
    if (threadIdx.x == 1023) bsum[b] = buf[1023];
    if (b == 0 && threadIdx.x == 0) rp[0] = 0;
}

__global__ void scan2(int* __restrict__ bsum, int nb) {
    int lane = threadIdx.x;
    int v = (lane < nb) ? bsum[lane] : 0;
    for (int off = 1; off < 64; off <<= 1) {
        int t = __shfl_up(v, off);
        if (lane >= off) v += t;
    }
    if (lane < nb) bsum[lane] = v;
}

__global__ __launch_bounds__(1024) void scan3(int* __restrict__ rp, const int* __restrict__ bsum, int n) {
    int b = blockIdx.x;
    if (b == 0) return;
    int i = b * 1024 + threadIdx.x;
    if (i < n) rp[i + 1] += bsum[b - 1];
}

__global__ void gbase_kernel(const int* __restrict__ histD, const int* __restrict__ rp,
                             int* __restrict__ gbase, int N) {
    int n = blockIdx.x * blockDim.x + threadIdx.x;
    if (n >= N) return;
    int run = rp[n];
    for (int b = 0; b < NB_E; b++) {
        gbase[(size_t)b * N + n] = run;
        run += histD[(size_t)b * N + n];
    }
}

__global__ __launch_bounds__(HTPB) void scatter2_kernel(
    const int* __restrict__ src, const int* __restrict__ dst,
    const int* __restrict__ gbase, const float* __restrict__ ns,
    int2* __restrict__ payload, int E, int N, int nhalf, int chunk) {
    __shared__ int h[NHALF_LDS];
    int b = blockIdx.x, half = blockIdx.y;
    int lo = half * nhalf;
    int hi = min(lo + nhalf, N);
    int cnt = hi - lo;
    for (int i = threadIdx.x; i < cnt; i += HTPB) h[i] = 0;
    __syncthreads();
    int beg = b * chunk, end = min(E, beg + chunk);
    for (int i = beg + threadIdx.x; i < end; i += HTPB) {
        int d = dst[i];
        if (d >= lo && d < hi) {
            int s = src[i];
            int rank = atomicAdd(&h[d - lo], 1);
            int pos = gbase[(size_t)b * N + d] + rank;
            payload[pos] = make_int2(s, __float_as_int(ns[s]));
        }
    }
}

// t[d] = nd[d] * sum_e w_e   (padding has w=0)
__global__ __launch_bounds__(256) void st_kernel(const int* __restrict__ rp,
                                                 const int2* __restrict__ payload,
                                                 const float* __restrict__ nd,
                                                 float* __restrict__ tv, int n) {
    int d = blockIdx.x * 4 + (threadIdx.x >> 6);
    if (d >= n) return;
    int lane = threadIdx.x & 63;
    int beg = rp[d], end = rp[d + 1];
    float acc = 0.f;
    for (int e = beg + lane; e < end; e += 64) acc += __int_as_float(payload[e].y);
    for (int off = 32; off > 0; off >>= 1) acc += __shfl_down(acc, off);
    if (lane == 0) tv[d] = acc * nd[d];
}

// ---------------- small GEMV (fp32) ----------------

__global__ void gemv_rows(const float* __restrict__ vec, const float* __restrict__ Mat,
                          const float* __restrict__ bias, float* __restrict__ out, int n) {
    int j = blockIdx.x;
    const float* row = Mat + (size_t)j * n;
    float s = 0.f;
    for (int i = threadIdx.x; i < n; i += blockDim.x) s += vec[i] * row[i];
    __shared__ float red[TPB];
    red[threadIdx.x] = s;
    __syncthreads();
    for (int o = TPB / 2; o > 0; o >>= 1) {
        if (threadIdx.x < o) red[threadIdx.x] += red[threadIdx.x + o];
        __syncthreads();
    }
    if (threadIdx.x == 0) out[j] = red[0] + (bias ? bias[j] : 0.f);
}

__global__ __launch_bounds__(64) void u_kernel(const float* __restrict__ ce, const float* __restrict__ W1,
                                               float* __restrict__ u, int FD, int IF) {
    int j = blockIdx.x;
    int lane = threadIdx.x;
    float s = 0.f;
    for (int i = lane; i < FD; i += 64) s += ce[i] * W1[(size_t)i * IF + j];
    for (int off = 32; off > 0; off >>= 1) s += __shfl_down(s, off);
    if (lane == 0) u[j] = s;
}

// ---------------- conversion kernels ----------------

__global__ void pad_convert4(const float* __restrict__ in, int icols, int irows,
                             unsigned short* __restrict__ out, int ocols, int orows, int cpr) {
    int idx = blockIdx.x * blockDim.x + threadIdx.x;
    int row = idx / cpr;
    int c4 = (idx - row * cpr) * 4;
    if (row >= orows) return;
    float4 v = make_float4(0.f, 0.f, 0.f, 0.f);
    if (row < irows && c4 < icols)
        v = *(const float4*)(in + (size_t)row * icols + c4);
    u16x4_t o;
    o[0] = f2bf(v.x); o[1] = f2bf(v.y); o[2] = f2bf(v.z); o[3] = f2bf(v.w);
    *(u16x4_t*)(out + (size_t)row * ocols + c4) = o;
}

__global__ void transpose_pad(const float* __restrict__ W, int rows, int cols, int ldw,
                              unsigned short* __restrict__ out, int orows, int ocols) {
    __shared__ float tile[32][33];
    int k0 = blockIdx.x * 32, n0 = blockIdx.y * 32;
    int tx = threadIdx.x, ty = threadIdx.y;  // 32 x 8
    for (int i = 0; i < 32; i += 8) {
        int k = k0 + ty + i, n = n0 + tx;
        tile[ty + i][tx] = (k < rows && n < cols) ? W[(size_t)k * ldw + n] : 0.f;
    }
    __syncthreads();
    for (int i = 0; i < 32; i += 8) {
        int n = n0 + ty + i, k = k0 + tx;
        if (n < orows && k < ocols) out[(size_t)n * ocols + k] = f2bf(tile[tx][ty + i]);
    }
}

// ---------------- bf16 MFMA GEMM (2-phase double-buffered pipeline) ----------------
// A padded to gridDim.y*128 rows. XCD-aware bijective block swizzle.
// Staging via global_load_lds (16B/lane), source pre-swizzled, LDS dest linear.
// Pipeline: stage(next) issued BEFORE compute(cur); one vmcnt-drain+barrier per K-step.
__global__ __launch_bounds__(256) void mfma_gemm(
    const unsigned short* __restrict__ A, const unsigned short* __restrict__ Bt,
    const float* __restrict__ bias, const float* __restrict__ rowscale,
    const float* __restrict__ tvec, const float* __restrict__ uvec,
    const float* __restrict__ w3, float* __restrict__ zout,
    unsigned short* __restrict__ C, int M, int Nn, int Kp, int Cld, int relu) {
    __shared__ unsigned short As[2][128 * 32];
    __shared__ unsigned short Bs[2][128 * 32];
    int tid = threadIdx.x;
    int lane = tid & 63;
    int wave = tid >> 6;
    int wm = wave >> 1, wn = wave & 1;  // 2x2 waves, each 64x64
    int lg = lane >> 4, lt = lane & 15;

    // bijective XCD swizzle (m204)
    int nwg = gridDim.x * gridDim.y;
    int hid = blockIdx.y * gridDim.x + blockIdx.x;
    int q = nwg >> 3, r8 = nwg & 7;
    int xcd = hid & 7, pos = hid >> 3;
    int wg = (xcd < r8 ? xcd * (q + 1) : r8 * (q + 1) + (xcd - r8) * q) + pos;
    int row0 = (wg / gridDim.x) * 128, col0 = (wg % gridDim.x) * 128;

    f32x4_t acc[4][4] = {};

    auto stage = [&](int b, int k0) {
#pragma unroll
        for (int i = 0; i < 2; i++) {
            int cid = tid + i * 256;
            int r = cid >> 2, c = cid & 3;
            int sw = c ^ ((r >> 1) & 3);  // pre-swizzle the SOURCE; LDS dest linear
            gload16(A + (size_t)(row0 + r) * Kp + k0 + (sw << 3), As[b] + cid * 8);
            gload16(Bt + (size_t)(col0 + r) * Kp + k0 + (sw << 3), Bs[b] + cid * 8);
        }
    };

    int nk = Kp >> 5;
    stage(0, 0);
    __syncthreads();  // drains vmcnt(0): buf0 ready

    int cur = 0;
    for (int kp = 0; kp < nk; kp++) {
        if (kp + 1 < nk) stage(cur ^ 1, (kp + 1) << 5);  // issue next-tile loads FIRST
        bf16x8_t af[4], bfr[4];
#pragma unroll
        for (int mi = 0; mi < 4; mi++) {
            int r = wm * 64 + mi * 16 + lt;
            int sw = lg ^ ((r >> 1) & 3);
            af[mi] = *(const bf16x8_t*)(As[cur] + r * 32 + sw * 8);
        }
#pragma unroll
        for (int ni = 0; ni < 4; ni++) {
            int r = wn * 64 + ni * 16 + lt;
            int sw = lg ^ ((r >> 1) & 3);
            bfr[ni] = *(const bf16x8_t*)(Bs[cur] + r * 32 + sw * 8);
        }
#pragma unroll
        for (int mi = 0; mi < 4; mi++)
#pragma unroll
            for (int ni = 0; ni < 4; ni++)
                acc[mi][ni] = __builtin_amdgcn_mfma_f32_16x16x32_bf16(af[mi], bfr[ni], acc[mi][ni], 0, 0, 0);
        __syncthreads();  // drain vmcnt(0) (next buf ready) + all waves done reading cur
        cur ^= 1;
    }

#pragma unroll
    for (int mi = 0; mi < 4; mi++) {
#pragma unroll
        for (int r = 0; r < 4; r++) {
            int row = row0 + wm * 64 + mi * 16 + lg * 4 + r;
            if (row >= M) continue;
            float rs = rowscale ? rowscale[row] : 1.f;
            float tvr = tvec ? tvec[row] : 0.f;
            float zp = 0.f;
#pragma unroll
            for (int ni = 0; ni < 4; ni++) {
                int colb = col0 + wn * 64 + ni * 16 + lt;
                float v = 0.f;
                if (colb < Nn) {
                    v = acc[mi][ni][r] * rs;
                    if (bias) v += bias[colb];
                    if (tvec) v += tvr * uvec[colb];
                    if (relu) v = fmaxf(v, 0.f);
                    if (w3) zp += v * w3[colb];
                }
                if (C) C[(size_t)row * Cld + colb] = f2bf(v);
            }
            if (w3) {
                zp += __shfl_xor(zp, 1);
                zp += __shfl_xor(zp, 2);
                zp += __shfl_xor(zp, 4);
                zp += __shfl_xor(zp, 8);
                if (lt == 0) atomicAdd(&zout[row], zp);
            }
        }
    }
}

// ---------------- SpMM (CSR gather, payload, 8-edge unroll, tail-free) ----------------
__global__ __launch_bounds__(256) void spmm_bf16_cols(
    const int* __restrict__ rp, const int2* __restrict__ payload,
    const unsigned short* __restrict__ X, unsigned short* __restrict__ Y,
    int n, int ld, int c0) {
    int node = blockIdx.x * 4 + (threadIdx.x >> 6);
    if (node >= n) return;
    int lane = threadIdx.x & 63;
    const unsigned short* Xo = X + c0 + lane * 4;
    int beg = rp[node], end = rp[node + 1];
    float acc[4] = {};
    for (int e = beg; e < end; e += 8) {
        int2 p[8];
#pragma unroll
        for (int j = 0; j < 8; j++) p[j] = payload[e + j];
        u16x4_t v[8];
#pragma unroll
        for (int j = 0; j < 8; j++) v[j] = *(const u16x4_t*)(Xo + (size_t)p[j].x * ld);
#pragma unroll
        for (int j = 0; j < 8; j++) {
            float w = __int_as_float(p[j].y);
#pragma unroll
            for (int c = 0; c < 4; c++) acc[c] += w * bf2f(v[j][c]);
        }
    }
    u16x4_t o;
#pragma unroll
    for (int c = 0; c < 4; c++) o[c] = f2bf(acc[c]);
    *(u16x4_t*)(Y + (size_t)node * ld + c0 + lane * 4) = o;
}

// ---------------- z path ----------------

__global__ __launch_bounds__(256) void z_gather(const int* __restrict__ rp,
                                                const int2* __restrict__ payload,
                                                const float* __restrict__ z,
                                                const float* __restrict__ nd, const float* __restrict__ b3,
                                                float* __restrict__ o, int n) {
    int d = blockIdx.x * 4 + (threadIdx.x >> 6);
    if (d >= n) return;
    int lane = threadIdx.x & 63;
    int beg = rp[d], end = rp[d + 1];
    float acc = 0.f;
    for (int e = beg + lane; e < end; e += 64) {
        int2 p = payload[e];
        acc += __int_as_float(p.y) * z[p.x];
    }
    for (int off = 32; off > 0; off >>= 1) acc += __shfl_down(acc, off);
    if (lane == 0) o[d] = fmaxf(nd[d] * acc + b3[0], 0.f);
}

// ---------------- launch ----------------

extern "C" void kernel_launch(void* const* d_in, const int* in_sizes, int n_in,
                              void* d_out, int out_size, void* d_ws, size_t ws_size,
                              hipStream_t stream) {
    const float* class_embed = (const float*)d_in[0];
    const float* all_glove   = (const float*)d_in[1];
    const float* W_word = (const float*)d_in[2];
    const float* b_word = (const float*)d_in[3];
    const float* W_img  = (const float*)d_in[4];
    const float* b_img  = (const float*)d_in[5];
    const float* W1 = (const float*)d_in[6];
    const float* b1 = (const float*)d_in[7];
    const float* W2 = (const float*)d_in[8];
    const float* b2 = (const float*)d_in[9];
    const float* W3 = (const float*)d_in[10];
    const float* b3 = (const float*)d_in[11];
    const float* W_fin = (const float*)d_in[12];
    const float* b_fin = (const float*)d_in[13];
    const int* src = (const int*)d_in[14];
    const int* dst = (const int*)d_in[15];

    const int N   = in_sizes[0];
    const int GLV = in_sizes[1] / N;   // 300
    const int FD  = in_sizes[5];       // 254
    const int IF  = in_sizes[7];       // 508
    const int E   = in_sizes[14];

    const int GLVp = 320;
    const int FDp  = 256;
    const int IFp  = 512;
    const int Mp   = (N + 127) & ~127;     // padded row count for GEMM A operands
    const int EP   = E + 8 * N;            // padded edge capacity
    const int nhalf = (N + 1) / 2;         // <= NHALF_LDS
    const int chunk = (E + NB_E - 1) / NB_E;

    char* base = (char*)d_ws;
    size_t off = 0;
    auto alloc = [&](size_t bytes) -> void* {
        void* p = base + off;
        off = (off + bytes + 255) & ~(size_t)255;
        return p;
    };

    float* ns  = (float*)alloc((size_t)N * 4);
    float* nd  = (float*)alloc((size_t)N * 4);
    float* z   = (float*)alloc((size_t)N * 4);   // zeroed (atomic accum)
    float* tv  = (float*)alloc((size_t)N * 4);
    float* ce  = (float*)alloc((size_t)FD * 4);
    float* u   = (float*)alloc((size_t)IF * 4);
    float* ov  = (float*)alloc((size_t)N * 4);
    int* degp  = (int*)alloc((size_t)N * 4);
    int* rp    = (int*)alloc((size_t)(N + 1) * 4);
    int* bsum  = (int*)alloc(64 * 4);
    int* histD = (int*)alloc((size_t)NB_E * N * 4);
    int* histS = (int*)alloc((size_t)NB_E * N * 4);
    int* gbase = (int*)alloc((size_t)NB_E * N * 4);
    int2* payload = (int2*)alloc((size_t)EP * 8);
    unsigned short* WwP  = (unsigned short*)alloc((size_t)FDp * GLVp * 2);
    unsigned short* W1hT = (unsigned short*)alloc((size_t)IFp * FDp * 2);
    unsigned short* W2T  = (unsigned short*)alloc((size_t)IFp * IFp * 2);
    unsigned short* glove_bf = (unsigned short*)alloc((size_t)Mp * GLVp * 2);
    unsigned short* we       = (unsigned short*)alloc((size_t)Mp * FDp * 2);
    unsigned short* h12      = (unsigned short*)alloc((size_t)Mp * IFp * 2);
    unsigned short* aggwe = glove_bf;   // [Mp][256] after glove dead
    unsigned short* agg2  = glove_bf;   // [Mp][512] spans glove+we regions
    unsigned short* h1 = h12;

    hipMemsetAsync(z, 0, (size_t)N * 4, stream);
    hipMemsetAsync(payload, 0, (size_t)EP * 8, stream);  // padding edges: {s=0, w=0}

    int gN = (N + TPB - 1) / TPB;
    int nb = (N + 1023) / 1024;

    // CSR build: hist -> degrees/norms -> scan -> gbase -> rank-scatter
    {
        dim3 g(NB_E, 4);
        hist_kernel<<<g, HTPB, 0, stream>>>(src, dst, histD, histS, E, N, nhalf, chunk);
    }
    degreduce_kernel<<<gN, TPB, 0, stream>>>(histD, histS, ns, nd, degp, N);
    scan1<<<nb, 1024, 0, stream>>>(degp, rp, bsum, N);
    scan2<<<1, 64, 0, stream>>>(bsum, nb);
    scan3<<<nb, 1024, 0, stream>>>(rp, bsum, N);
    gbase_kernel<<<gN, TPB, 0, stream>>>(histD, rp, gbase, N);
    {
        dim3 g(NB_E, 2);
        scatter2_kernel<<<g, HTPB, 0, stream>>>(src, dst, gbase, ns, payload, E, N, nhalf, chunk);
    }
    st_kernel<<<(N + 3) / 4, 256, 0, stream>>>(rp, payload, nd, tv, N);

    // ce = class_embed @ W_img.T + b_img ; u = ce @ W1[:FD, :]
    gemv_rows<<<FD, TPB, 0, stream>>>(class_embed, W_img, b_img, ce, N);
    u_kernel<<<IF, 64, 0, stream>>>(ce, W1, u, FD, IF);

    // conversions (glove zero-padded to Mp rows so GEMM A-stage needs no M guard)
    {
        int cpr = GLVp / 4;
        int tot = Mp * cpr;
        pad_convert4<<<(tot + 255) / 256, 256, 0, stream>>>(all_glove, GLV, N, glove_bf, GLVp, Mp, cpr);
        int tot2 = FDp * cpr;
        pad_convert4<<<(tot2 + 255) / 256, 256, 0, stream>>>(W_word, GLV, FD, WwP, GLVp, FDp, cpr);
    }
    {
        dim3 g(FDp / 32, IFp / 32);
        transpose_pad<<<g, dim3(32, 8), 0, stream>>>(W1 + (size_t)FD * IF, FD, IF, IF, W1hT, IFp, FDp);
    }
    {
        dim3 g(IFp / 32, IFp / 32);
        transpose_pad<<<g, dim3(32, 8), 0, stream>>>(W2, IF, IF, IF, W2T, IFp, IFp);
    }

    int mtiles = Mp / 128;

    // we = all_glove @ W_word.T + b_word   [N][256] bf16
    {
        dim3 g(FDp / 128, mtiles);
        mfma_gemm<<<g, 256, 0, stream>>>(glove_bf, WwP, b_word, nullptr, nullptr, nullptr,
                                         nullptr, nullptr, we, N, FD, GLVp, FDp, 0);
    }
    // SpMM1: aggwe = sum w*we[s]   [N][256]
    spmm_bf16_cols<<<(N + 3) / 4, 256, 0, stream>>>(rp, payload, we, aggwe, N, FDp, 0);
    // h1 = relu(nd[r]*(aggwe @ W1[FD:,:]) + tv[r]*u[c] + b1)   [N][512]
    {
        dim3 g(IFp / 128, mtiles);
        mfma_gemm<<<g, 256, 0, stream>>>(aggwe, W1hT, b1, nd, tv, u,
                                         nullptr, nullptr, h1, N, IF, FDp, IFp, 1);
    }
    // SpMM2: agg2 = sum w*h1[s]   [N][512]  (two column passes)
    spmm_bf16_cols<<<(N + 3) / 4, 256, 0, stream>>>(rp, payload, h1, agg2, N, IFp, 0);
    spmm_bf16_cols<<<(N + 3) / 4, 256, 0, stream>>>(rp, payload, h1, agg2, N, IFp, 256);
    // gemm2 fused: z[r] = relu(nd[r]*(agg2 @ W2) + b2) @ W3   (no C write)
    {
        dim3 g(IFp / 128, mtiles);
        mfma_gemm<<<g, 256, 0, stream>>>(agg2, W2T, b2, nd, nullptr, nullptr,
                                         W3, z, nullptr, N, IF, IFp, IFp, 1);
    }
    // o = relu(nd * gather(w*z) + b3)
    z_gather<<<(N + 3) / 4, 256, 0, stream>>>(rp, payload, z, nd, b3, ov, N);
    // out = o @ W_fin.T + b_fin
    gemv_rows<<<FD, TPB, 0, stream>>>(ov, W_fin, b_fin, (float*)d_out, N);
}